// Round 2
// 209.602 us; speedup vs baseline: 1.0355x; 1.0355x over previous
//
#include <hip/hip_runtime.h>
#include <hip/hip_bf16.h>

#define B_    16
#define C_    512
#define S_    1024      // H*W
#define NGRP  32
#define CPG   16

typedef __attribute__((ext_vector_type(8))) short  short8;
typedef __attribute__((ext_vector_type(4))) short  short4v;
typedef __attribute__((ext_vector_type(4))) float  floatx4;

__device__ __forceinline__ unsigned short f2bf(float f) {
    __hip_bfloat16 h = __float2bfloat16(f);
    unsigned short u;
    __builtin_memcpy(&u, &h, 2);
    return u;
}

// ---------------------------------------------------------------------------
// Fused GroupNorm (+transpose to xnT[b][s][c] bf16), single pass over x.
// ---------------------------------------------------------------------------
__global__ __launch_bounds__(256)
void gn_fused_kernel(const float* __restrict__ x, const float* __restrict__ w,
                     const float* __restrict__ bias, __hip_bfloat16* __restrict__ xnT) {
    int bg = blockIdx.x;
    int b = bg >> 5, g = bg & 31;
    const float4* xp = (const float4*)(x + (size_t)bg * (CPG * S_));
    int tid = threadIdx.x;

    float4 vv[16];
    float s = 0.f, ss = 0.f;
#pragma unroll
    for (int r = 0; r < 16; ++r) {
        float4 v = xp[r * 256 + tid];
        vv[r] = v;
        s  += v.x + v.y + v.z + v.w;
        ss += v.x*v.x + v.y*v.y + v.z*v.z + v.w*v.w;
    }
    for (int off = 32; off > 0; off >>= 1) {
        s  += __shfl_down(s, off);
        ss += __shfl_down(ss, off);
    }
    __shared__ float red[2][4];
    __shared__ float msh[2];
    int wid = tid >> 6, lane = tid & 63;
    if (lane == 0) { red[0][wid] = s; red[1][wid] = ss; }
    __syncthreads();
    if (tid == 0) {
        float a = 0.f, c = 0.f;
        for (int i = 0; i < 4; ++i) { a += red[0][i]; c += red[1][i]; }
        float mean = a / (float)(CPG * S_);
        float var  = c / (float)(CPG * S_) - mean * mean;
        msh[0] = mean;
        msh[1] = rsqrtf(var + 1e-5f);
    }
    __syncthreads();
    float mean = msh[0], inv = msh[1];

    float sc[16], sh[16];
#pragma unroll
    for (int c = 0; c < 16; ++c) {
        float wc = w[g * 16 + c];
        sc[c] = inv * wc;
        sh[c] = bias[g * 16 + c] - mean * inv * wc;
    }

#pragma unroll
    for (int kk = 0; kk < 4; ++kk) {
        unsigned short outp[16];
#pragma unroll
        for (int c = 0; c < 16; ++c) {
            float v = (kk == 0) ? vv[c].x : (kk == 1) ? vv[c].y : (kk == 2) ? vv[c].z : vv[c].w;
            outp[c] = f2bf(v * sc[c] + sh[c]);
        }
        int srow = 4 * tid + kk;
        unsigned short* dst = (unsigned short*)xnT + ((size_t)(b * S_ + srow) * C_ + g * 16);
        *(short8*)dst       = *(short8*)outp;
        *(short8*)(dst + 8) = *(short8*)(outp + 8);
    }
}

// ---------------------------------------------------------------------------
// Prep: weight transposes->bf16, wp convert, parallel bias matvecs.
// ---------------------------------------------------------------------------
__global__ __launch_bounds__(256)
void prep_kernel(const float* __restrict__ qkv_w, const float* __restrict__ proj_w,
                 const float* __restrict__ qkv_b,
                 unsigned short* __restrict__ bufX,   // [WkT | wp_bf]
                 unsigned short* __restrict__ bufY,   // [WqT | WvT]
                 float* __restrict__ bqWk, float* __restrict__ biasvp)
{
    int blk = blockIdx.x;
    int tid = threadIdx.x;
    if (blk < 192) {
        __shared__ float T[64][65];
        int mat = blk >> 6, tile = blk & 63;
        int r0 = (tile >> 3) * 64, c0 = (tile & 7) * 64;  // dst[r0+i][c0+j] = src[c0+j][r0+i]
        const float* src; unsigned short* dst;
        if (mat == 0)      { src = qkv_w + 512 * 512;  dst = bufX; }
        else if (mat == 1) { src = qkv_w;              dst = bufY; }
        else               { src = qkv_w + 1024 * 512; dst = bufY + 262144; }
#pragma unroll
        for (int rr = 0; rr < 4; ++rr) {
            int sr = rr * 16 + (tid >> 4);
            int sc = (tid & 15) * 4;
            float4 v = *(const float4*)(src + (size_t)(c0 + sr) * 512 + r0 + sc);
            T[sc][sr] = v.x; T[sc + 1][sr] = v.y; T[sc + 2][sr] = v.z; T[sc + 3][sr] = v.w;
        }
        __syncthreads();
#pragma unroll
        for (int rr = 0; rr < 4; ++rr) {
            int dr = rr * 16 + (tid >> 4);
            int dc = (tid & 15) * 4;
            short4v o;
            o[0] = (short)f2bf(T[dr][dc]);     o[1] = (short)f2bf(T[dr][dc + 1]);
            o[2] = (short)f2bf(T[dr][dc + 2]); o[3] = (short)f2bf(T[dr][dc + 3]);
            *(short4v*)(dst + (size_t)(r0 + dr) * 512 + c0 + dc) = o;
        }
    } else if (blk < 256) {
        unsigned short* wp = bufX + 262144;
#pragma unroll
        for (int t = 0; t < 4; ++t) {
            int i = (blk - 192) * 4096 + t * 1024 + tid * 4;
            float4 v = *(const float4*)(proj_w + i);
            short4v o;
            o[0] = (short)f2bf(v.x); o[1] = (short)f2bf(v.y);
            o[2] = (short)f2bf(v.z); o[3] = (short)f2bf(v.w);
            *(short4v*)(wp + i) = o;
        }
    } else if (blk < 264) {
        int sub = blk - 256;
        int j = (sub & 1) * 256 + tid;
        int o0 = (sub >> 1) * 128;
        float acc = 0.f;
#pragma unroll 8
        for (int oo = 0; oo < 128; ++oo) {
            int o = o0 + oo;
            acc += qkv_b[o] * qkv_w[(size_t)(512 + o) * 512 + j];
        }
        atomicAdd(&bqWk[j], acc);
    } else {
        int wv = tid >> 6, lane = tid & 63;
        int c = (blk - 264) * 4 + wv;
        float s = 0.f;
#pragma unroll
        for (int t = 0; t < 8; ++t)
            s += proj_w[(size_t)c * 512 + t * 64 + lane] * qkv_b[1024 + t * 64 + lane];
        for (int off = 32; off > 0; off >>= 1) s += __shfl_down(s, off);
        if (lane == 0) biasvp[c] = s;
    }
}

// ---------------------------------------------------------------------------
// Uniform NT bf16 MFMA GEMM, BK=64. C[m][n] = alpha*sum A[m][k]B[n][k].
// ---------------------------------------------------------------------------
template<int BIAS_MODE, bool OUT_BF16, bool RESID, bool SWIZ, int KTOT>
__global__ __launch_bounds__(256)
void mfma_gemm(const unsigned short* __restrict__ A, const unsigned short* __restrict__ Bm,
               const float* __restrict__ bias, const float* __restrict__ resid,
               void* __restrict__ Yv,
               int lda, int ldb, int ldy,
               size_t sA, size_t sB, size_t sY, size_t sR, float alpha,
               int ntsh, int nxsh)
{
    __shared__ unsigned short As[2 * 128 * 32];
    __shared__ unsigned short Bs[2 * 128 * 32];
    int bx, by, bz;
    if (SWIZ) {
        int lin = blockIdx.x;
        int xcd = lin & 7, sup = lin >> 3;
        bz = xcd + ((sup >> ntsh) << 3);
        int tile = sup & ((1 << ntsh) - 1);
        bx = tile & ((1 << nxsh) - 1);
        by = tile >> nxsh;
    } else { bx = blockIdx.x; by = blockIdx.y; bz = blockIdx.z; }

    const unsigned short* Ab = A  + (size_t)bz * sA;
    const unsigned short* Bb = Bm + (size_t)bz * sB;
    const int tid = threadIdx.x, wave = tid >> 6, lane = tid & 63;
    const int m0 = by * 128, n0 = bx * 128;
    const int wr = wave >> 1, wc = wave & 1, lr = lane & 15, kq = lane >> 4;
    const int row0 = tid >> 2, kc0 = (tid & 3) << 3;

    floatx4 acc[4][4] = {};

    for (int k0 = 0; k0 < KTOT; k0 += 64) {
        __syncthreads();
#pragma unroll
        for (int kk = 0; kk < 2; ++kk) {
#pragma unroll
            for (int r = 0; r < 2; ++r) {
                const unsigned short* ga = Ab + (size_t)(m0 + r * 64 + row0) * lda + k0 + kk * 32 + kc0;
                __builtin_amdgcn_global_load_lds(
                    (const __attribute__((address_space(1))) void*)ga,
                    (__attribute__((address_space(3))) void*)(As + kk * 4096 + (r * 256 + wave * 64) * 8),
                    16, 0, 0);
                const unsigned short* gb = Bb + (size_t)(n0 + r * 64 + row0) * ldb + k0 + kk * 32 + kc0;
                __builtin_amdgcn_global_load_lds(
                    (const __attribute__((address_space(1))) void*)gb,
                    (__attribute__((address_space(3))) void*)(Bs + kk * 4096 + (r * 256 + wave * 64) * 8),
                    16, 0, 0);
            }
        }
        __syncthreads();

#pragma unroll
        for (int kk = 0; kk < 2; ++kk) {
            short8 af[4], bfr[4];
#pragma unroll
            for (int i = 0; i < 4; ++i)
                af[i] = *(const short8*)&As[kk * 4096 + (wr * 64 + i * 16 + lr) * 32 + kq * 8];
#pragma unroll
            for (int j = 0; j < 4; ++j)
                bfr[j] = *(const short8*)&Bs[kk * 4096 + (wc * 64 + j * 16 + lr) * 32 + kq * 8];
#pragma unroll
            for (int i = 0; i < 4; ++i)
#pragma unroll
                for (int j = 0; j < 4; ++j)
                    acc[i][j] = __builtin_amdgcn_mfma_f32_16x16x32_bf16(af[i], bfr[j], acc[i][j], 0, 0, 0);
        }
    }

    const size_t ybase = (size_t)bz * sY;
    const size_t rbase = (size_t)bz * sR;
#pragma unroll
    for (int i = 0; i < 4; ++i) {
#pragma unroll
        for (int r = 0; r < 4; ++r) {
            int m = m0 + wr * 64 + i * 16 + kq * 4 + r;
            float bm = (BIAS_MODE == 1) ? bias[m] : 0.f;
#pragma unroll
            for (int j = 0; j < 4; ++j) {
                int n = n0 + wc * 64 + j * 16 + lr;
                float vv = acc[i][j][r] * alpha + bm;
                if (BIAS_MODE == 2) vv += bias[n];
                if (RESID) vv += resid[rbase + (size_t)m * ldy + n];
                if (OUT_BF16)
                    ((__hip_bfloat16*)Yv)[ybase + (size_t)m * ldy + n] = __float2bfloat16(vv);
                else
                    ((float*)Yv)[ybase + (size_t)m * ldy + n] = vv;
            }
        }
    }
}

// ---------------------------------------------------------------------------
// Scores^T + fused 32-key-chunk softmax + transposed P write.
// 256x256 tile, 8-phase schedule (T3+T4): BK=64, 2-deep LDS double buffer,
// counted s_waitcnt vmcnt(6) at K-tile boundaries (drain only for t>=6).
// T2: XOR swizzle byte^=((row&7)<<4); T5: setprio around MFMA clusters.
//
// LDS slot lifetimes (race-audited):
//   A half0 of buf: read in phases 0 (rows 0-63) and 2 (rows 64-127)
//     -> overwrite (A0(t+2)) may only be issued in phase 3.
//   A half1 of buf^1 (tile t-1): last read iter t-1 phase 2 -> A1(t+1) safe
//     in phase 0.
//   B half0/half1 of buf: read in phases 0 (nh=0) and 1 (nh=1)
//     -> overwrites (B0/B1 (t+2)) safe from phase 2 onward.
// Per-iter issue order: A1(t+1) [ph0], B0(t+2) [ph2], A0(t+2)+B1(t+2) [ph3]
//   -> 3 stages (6 loads) younger than A1(t+1), so vmcnt(6) at the K-tile
//   boundary proves tile t+1 has fully landed. For t>=6 the younger stages
//   are skipped, so drain with vmcnt(0) there (tail fix).
// ---------------------------------------------------------------------------
__global__ __launch_bounds__(512)
void scores_softmax8(const unsigned short* __restrict__ A,   // xnT (keys)
                     const unsigned short* __restrict__ Bm,  // u (queries)
                     unsigned short* __restrict__ P)
{
    __shared__ __align__(16) unsigned short lds[65536];   // 128 KiB
    char* asb = (char*)lds;            // A: [2 buf][2 half][128 rows][128 B]
    char* bsb = (char*)lds + 65536;    // B: same

    const int bid = blockIdx.x;
    const int bz = bid >> 4, t16 = bid & 15;
    const int by = t16 >> 2, bx = t16 & 3;
    const int m0 = by << 8, n0 = bx << 8;      // m = key, n = sq

    const size_t sAB = (size_t)S_ * 512;
    const unsigned short* Ab = A  + (size_t)bz * sAB;
    const unsigned short* Bb = Bm + (size_t)bz * sAB;

    const int tid = threadIdx.x, wave = tid >> 6, lane = tid & 63;
    const int wr = wave >> 2, wc = wave & 3;   // 2 x 4 wave grid
    const int lr = lane & 15, kq = lane >> 4;
    const int swz = (lr & 7) << 4;

    floatx4 acc[8][4] = {};
    short8 aF[4][2], bF[2][2][2];

    // stage one half-tile (128 rows x 64 k) -> 2 global_load_lds per thread.
    // LDS dest linear; global source pre-swizzled (inverse of read XOR).
    auto stage = [&](const unsigned short* __restrict__ G, int row0, int t,
                     char* base, int buf, int half) {
#pragma unroll
        for (int c = 0; c < 2; ++c) {
            int x = c * 8192 + tid * 16;
            int row = x >> 7;
            int colb = (x & 127) ^ ((row & 7) << 4);
            const unsigned short* ga = G + (((size_t)(row0 + row)) << 9) + (t << 6) + (colb >> 1);
            char* ldst = base + buf * 32768 + half * 16384 + c * 8192 + wave * 1024;
            __builtin_amdgcn_global_load_lds(
                (const __attribute__((address_space(1))) void*)ga,
                (__attribute__((address_space(3))) void*)ldst, 16, 0, 0);
        }
    };
    auto rdA = [&](int buf, int mh, int ii, int kk) {
        int byte = buf * 32768 + wr * 16384 + (mh * 64 + ii * 16 + lr) * 128
                 + ((kk * 64 + kq * 16) ^ swz);
        return *(const short8*)(asb + byte);
    };
    auto rdB = [&](int buf, int nh, int jj, int kk) {
        int trow = wc * 64 + (nh * 2 + jj) * 16 + lr;
        int byte = buf * 32768 + (trow >> 7) * 16384 + (trow & 127) * 128
                 + ((kk * 64 + kq * 16) ^ swz);
        return *(const short8*)(bsb + byte);
    };

    // prologue: tile0 (A0,B0,B1,A1) + tile1 (A0,B0,B1); vmcnt(6) => tile0 landed
    stage(Ab, m0,       0, asb, 0, 0);
    stage(Bb, n0,       0, bsb, 0, 0);
    stage(Bb, n0 + 128, 0, bsb, 0, 1);
    stage(Ab, m0 + 128, 0, asb, 0, 1);
    stage(Ab, m0,       1, asb, 1, 0);
    stage(Bb, n0,       1, bsb, 1, 0);
    stage(Bb, n0 + 128, 1, bsb, 1, 1);
    asm volatile("s_waitcnt vmcnt(6)" ::: "memory");
    __builtin_amdgcn_s_barrier();

    for (int t = 0; t < 8; ++t) {
        const int buf = t & 1;
        // ---- phase 0: quad (mh=0, nh=0); stage A1(t+1) -> buf^1 (safe)
#pragma unroll
        for (int ii = 0; ii < 4; ++ii) { aF[ii][0] = rdA(buf, 0, ii, 0); aF[ii][1] = rdA(buf, 0, ii, 1); }
#pragma unroll
        for (int jj = 0; jj < 2; ++jj) { bF[0][jj][0] = rdB(buf, 0, jj, 0); bF[0][jj][1] = rdB(buf, 0, jj, 1); }
        if (t < 7) stage(Ab, m0 + 128, t + 1, asb, (t + 1) & 1, 1);
        __builtin_amdgcn_s_barrier();
        asm volatile("s_waitcnt lgkmcnt(0)" ::: "memory");
        __builtin_amdgcn_s_setprio(1);
#pragma unroll
        for (int ii = 0; ii < 4; ++ii)
#pragma unroll
            for (int jj = 0; jj < 2; ++jj)
#pragma unroll
                for (int kk = 0; kk < 2; ++kk)
                    acc[ii][jj] = __builtin_amdgcn_mfma_f32_16x16x32_bf16(aF[ii][kk], bF[0][jj][kk], acc[ii][jj], 0, 0, 0);
        __builtin_amdgcn_s_setprio(0);
        __builtin_amdgcn_s_barrier();
        // ---- phase 1: quad (0,1); NO stage (A half0 still live until ph2)
#pragma unroll
        for (int jj = 0; jj < 2; ++jj) { bF[1][jj][0] = rdB(buf, 1, jj, 0); bF[1][jj][1] = rdB(buf, 1, jj, 1); }
        __builtin_amdgcn_s_barrier();
        asm volatile("s_waitcnt lgkmcnt(0)" ::: "memory");
        __builtin_amdgcn_s_setprio(1);
#pragma unroll
        for (int ii = 0; ii < 4; ++ii)
#pragma unroll
            for (int jj = 0; jj < 2; ++jj)
#pragma unroll
                for (int kk = 0; kk < 2; ++kk)
                    acc[ii][2 + jj] = __builtin_amdgcn_mfma_f32_16x16x32_bf16(aF[ii][kk], bF[1][jj][kk], acc[ii][2 + jj], 0, 0, 0);
        __builtin_amdgcn_s_setprio(0);
        __builtin_amdgcn_s_barrier();
        // ---- phase 2: quad (1,1); stage B0(t+2) (B half0 reads ended ph1)
#pragma unroll
        for (int ii = 0; ii < 4; ++ii) { aF[ii][0] = rdA(buf, 1, ii, 0); aF[ii][1] = rdA(buf, 1, ii, 1); }
        if (t < 6) stage(Bb, n0, t + 2, bsb, buf, 0);
        __builtin_amdgcn_s_barrier();
        asm volatile("s_waitcnt lgkmcnt(0)" ::: "memory");
        __builtin_amdgcn_s_setprio(1);
#pragma unroll
        for (int ii = 0; ii < 4; ++ii)
#pragma unroll
            for (int jj = 0; jj < 2; ++jj)
#pragma unroll
                for (int kk = 0; kk < 2; ++kk)
                    acc[4 + ii][2 + jj] = __builtin_amdgcn_mfma_f32_16x16x32_bf16(aF[ii][kk], bF[1][jj][kk], acc[4 + ii][2 + jj], 0, 0, 0);
        __builtin_amdgcn_s_setprio(0);
        __builtin_amdgcn_s_barrier();
        // ---- phase 3: quad (1,0), reg-resident operands; stage A0(t+2)
        //      (A half0 reads ended at ph2's closing barrier) + B1(t+2).
        //      K-tile boundary: vmcnt(6) steady-state, drain for t>=6.
        if (t < 6) {
            stage(Ab, m0,       t + 2, asb, buf, 0);
            stage(Bb, n0 + 128, t + 2, bsb, buf, 1);
        }
        __builtin_amdgcn_s_setprio(1);
#pragma unroll
        for (int ii = 0; ii < 4; ++ii)
#pragma unroll
            for (int jj = 0; jj < 2; ++jj)
#pragma unroll
                for (int kk = 0; kk < 2; ++kk)
                    acc[4 + ii][jj] = __builtin_amdgcn_mfma_f32_16x16x32_bf16(aF[ii][kk], bF[0][jj][kk], acc[4 + ii][jj], 0, 0, 0);
        __builtin_amdgcn_s_setprio(0);
        if (t < 6) { asm volatile("s_waitcnt vmcnt(6)" ::: "memory"); }
        else       { asm volatile("s_waitcnt vmcnt(0)" ::: "memory"); }
        __builtin_amdgcn_s_barrier();
    }

    // softmax over 32-key chunks (chunk = frag pair x kq cross-lane reduce);
    // write P^T tile [256 sq][256 key] into (reused) LDS, XOR-swizzled.
#pragma unroll
    for (int j = 0; j < 4; ++j) {
        int sqc = wc * 64 + j * 16 + lr;
        int srow = sqc * 512;
        int sxor = (sqc & 7) << 4;
#pragma unroll
        for (int h = 0; h < 4; ++h) {
            float v0[4], v1[4];
            float mx = -1e30f;
#pragma unroll
            for (int r = 0; r < 4; ++r) {
                v0[r] = acc[2 * h][j][r]     * 0.125f;
                v1[r] = acc[2 * h + 1][j][r] * 0.125f;
                mx = fmaxf(mx, fmaxf(v0[r], v1[r]));
            }
            mx = fmaxf(mx, __shfl_xor(mx, 16));
            mx = fmaxf(mx, __shfl_xor(mx, 32));
            float sm = 0.f;
#pragma unroll
            for (int r = 0; r < 4; ++r) {
                v0[r] = __expf(v0[r] - mx);
                v1[r] = __expf(v1[r] - mx);
                sm += v0[r] + v1[r];
            }
            sm += __shfl_xor(sm, 16);
            sm += __shfl_xor(sm, 32);
            float inv = 1.f / sm;
            short4v p0, p1;
#pragma unroll
            for (int r = 0; r < 4; ++r) {
                p0[r] = (short)f2bf(v0[r] * inv);
                p1[r] = (short)f2bf(v1[r] * inv);
            }
            int kb = (wr * 128 + h * 32 + kq * 4) * 2;
            *(short4v*)(asb + ((srow + kb) ^ sxor))      = p0;
            *(short4v*)(asb + ((srow + kb + 32) ^ sxor)) = p1;
        }
    }
    __syncthreads();

    // coalesced P store: per instruction 2 rows x 512 B contiguous
    const size_t pbase = ((size_t)bz << 20) + (size_t)n0 * 1024 + m0;
#pragma unroll
    for (int it = 0; it < 16; ++it) {
        int row = wave * 32 + it * 2 + (lane >> 5);
        int colb = (lane & 31) << 4;
        short8 v = *(const short8*)(asb + ((row * 512 + colb) ^ ((row & 7) << 4)));
        *(short8*)(P + pbase + (size_t)row * 1024 + (colb >> 1)) = v;
    }
}

// ---------------------------------------------------------------------------
extern "C" void kernel_launch(void* const* d_in, const int* in_sizes, int n_in,
                              void* d_out, int out_size, void* d_ws, size_t ws_size,
                              hipStream_t stream) {
    const float* x     = (const float*)d_in[0];
    const float* gn_w  = (const float*)d_in[1];
    const float* gn_b  = (const float*)d_in[2];
    const float* qkv_w = (const float*)d_in[3];
    const float* qkv_b = (const float*)d_in[4];
    const float* pr_w  = (const float*)d_in[5];
    const float* pr_b  = (const float*)d_in[6];
    float* out = (float*)d_out;

    char* w = (char*)d_ws;
    __hip_bfloat16* xnT  = (__hip_bfloat16*)w;                     // 16 MiB [16][1024][512]
    __hip_bfloat16* u    = (__hip_bfloat16*)(w + (16u << 20));     // 16 MiB [16][1024][512]
    __hip_bfloat16* Vp   = (__hip_bfloat16*)(w + (32u << 20));     // 16 MiB [16][512][1024]
    __hip_bfloat16* P    = (__hip_bfloat16*)(w + (48u << 20));     // 32 MiB [16][1024][1024]
    unsigned short* bufX = (unsigned short*)(w + (80u << 20));     // 1 MiB [WkT | wp_bf]
    unsigned short* bufY = (unsigned short*)(w + (81u << 20));     // 1 MiB [WqT | WvT]
    unsigned short* bufZ = (unsigned short*)(w + (82u << 20));     // 1 MiB [MT | W']
    float*          bqWk = (float*)(w + (83u << 20));              // 2 KiB
    float*          bvp  = (float*)(w + (83u << 20) + 4096);       // 2 KiB

    // 0) zero the bqWk accumulator (atomics target)
    hipMemsetAsync(bqWk, 0, 512 * sizeof(float), stream);

    // 1) prep: transposes -> bf16, wp convert, parallel bias matvecs
    prep_kernel<<<392, 256, 0, stream>>>(qkv_w, pr_w, qkv_b, bufX, bufY, bqWk, bvp);

    // 2) fused GroupNorm -> xnT
    gn_fused_kernel<<<B_ * NGRP, 256, 0, stream>>>(x, gn_w, gn_b, xnT);

    // 3) MT = WkT . WqT^T  (z=0)  and  W' = Wp . WvT^T  (z=1): 512x512x512 NT
    mfma_gemm<0, true, false, false, 512><<<dim3(4, 4, 2), 256, 0, stream>>>(
        bufX, bufY, nullptr, nullptr, bufZ,
        512, 512, 512, 262144, 262144, 262144, 0, 1.f, 0, 0);

    // 4) u = xnT . MT^T + bqWk[n]   M=16384, N=512, K=512
    mfma_gemm<2, true, false, false, 512><<<dim3(4, 128, 1), 256, 0, stream>>>(
        (const unsigned short*)xnT, bufZ, bqWk, nullptr, u,
        512, 512, 512, 0, 0, 0, 0, 1.f, 0, 0);

    // 5) V' = W' . xnT^T + bvp[m]   batched: M=512(c), N=1024(key), K=512
    mfma_gemm<1, true, false, true, 512><<<512, 256, 0, stream>>>(
        bufZ + 262144, (const unsigned short*)xnT, bvp, nullptr, Vp,
        512, 512, 1024, 0, (size_t)S_ * 512, (size_t)512 * S_, 0, 1.f, 5, 3);

    // 6) scores^T + fused softmax + transpose -> P[sq][key]  (8-phase 256^2)
    scores_softmax8<<<256, 512, 0, stream>>>(
        (const unsigned short*)xnT, (const unsigned short*)u, (unsigned short*)P);

    // 7) out = V' . P^T + pr_b[m] + x   batched: M=512(c), N=1024(sq), K=1024
    mfma_gemm<1, false, true, true, 1024><<<512, 256, 0, stream>>>(
        (const unsigned short*)Vp, (const unsigned short*)P, pr_b, x, out,
        1024, 1024, 1024, (size_t)512 * S_, (size_t)S_ * S_, (size_t)512 * S_,
        (size_t)512 * S_, 1.f, 5, 3);
}

// Round 4
// 197.768 us; speedup vs baseline: 1.0974x; 1.0598x over previous
//
#include <hip/hip_runtime.h>
#include <hip/hip_bf16.h>

#define B_    16
#define C_    512
#define S_    1024      // H*W
#define NGRP  32
#define CPG   16

typedef __attribute__((ext_vector_type(8))) short  short8;
typedef __attribute__((ext_vector_type(4))) short  short4v;
typedef __attribute__((ext_vector_type(4))) float  floatx4;

__device__ __forceinline__ unsigned short f2bf(float f) {
    __hip_bfloat16 h = __float2bfloat16(f);
    unsigned short u;
    __builtin_memcpy(&u, &h, 2);
    return u;
}

// ---------------------------------------------------------------------------
// Fused GroupNorm (+transpose to xnT[b][s][c] bf16), single pass over x.
// ---------------------------------------------------------------------------
__global__ __launch_bounds__(256)
void gn_fused_kernel(const float* __restrict__ x, const float* __restrict__ w,
                     const float* __restrict__ bias, __hip_bfloat16* __restrict__ xnT) {
    int bg = blockIdx.x;
    int b = bg >> 5, g = bg & 31;
    const float4* xp = (const float4*)(x + (size_t)bg * (CPG * S_));
    int tid = threadIdx.x;

    float4 vv[16];
    float s = 0.f, ss = 0.f;
#pragma unroll
    for (int r = 0; r < 16; ++r) {
        float4 v = xp[r * 256 + tid];
        vv[r] = v;
        s  += v.x + v.y + v.z + v.w;
        ss += v.x*v.x + v.y*v.y + v.z*v.z + v.w*v.w;
    }
    for (int off = 32; off > 0; off >>= 1) {
        s  += __shfl_down(s, off);
        ss += __shfl_down(ss, off);
    }
    __shared__ float red[2][4];
    __shared__ float msh[2];
    int wid = tid >> 6, lane = tid & 63;
    if (lane == 0) { red[0][wid] = s; red[1][wid] = ss; }
    __syncthreads();
    if (tid == 0) {
        float a = 0.f, c = 0.f;
        for (int i = 0; i < 4; ++i) { a += red[0][i]; c += red[1][i]; }
        float mean = a / (float)(CPG * S_);
        float var  = c / (float)(CPG * S_) - mean * mean;
        msh[0] = mean;
        msh[1] = rsqrtf(var + 1e-5f);
    }
    __syncthreads();
    float mean = msh[0], inv = msh[1];

    float sc[16], sh[16];
#pragma unroll
    for (int c = 0; c < 16; ++c) {
        float wc = w[g * 16 + c];
        sc[c] = inv * wc;
        sh[c] = bias[g * 16 + c] - mean * inv * wc;
    }

#pragma unroll
    for (int kk = 0; kk < 4; ++kk) {
        unsigned short outp[16];
#pragma unroll
        for (int c = 0; c < 16; ++c) {
            float v = (kk == 0) ? vv[c].x : (kk == 1) ? vv[c].y : (kk == 2) ? vv[c].z : vv[c].w;
            outp[c] = f2bf(v * sc[c] + sh[c]);
        }
        int srow = 4 * tid + kk;
        unsigned short* dst = (unsigned short*)xnT + ((size_t)(b * S_ + srow) * C_ + g * 16);
        *(short8*)dst       = *(short8*)outp;
        *(short8*)(dst + 8) = *(short8*)(outp + 8);
    }
}

// ---------------------------------------------------------------------------
// Prep: weight transposes->bf16, wp convert, parallel bias matvecs.
// ---------------------------------------------------------------------------
__global__ __launch_bounds__(256)
void prep_kernel(const float* __restrict__ qkv_w, const float* __restrict__ proj_w,
                 const float* __restrict__ qkv_b,
                 unsigned short* __restrict__ bufX,   // [WkT | wp_bf]
                 unsigned short* __restrict__ bufY,   // [WqT | WvT]
                 float* __restrict__ bqWk, float* __restrict__ biasvp)
{
    int blk = blockIdx.x;
    int tid = threadIdx.x;
    if (blk < 192) {
        __shared__ float T[64][65];
        int mat = blk >> 6, tile = blk & 63;
        int r0 = (tile >> 3) * 64, c0 = (tile & 7) * 64;  // dst[r0+i][c0+j] = src[c0+j][r0+i]
        const float* src; unsigned short* dst;
        if (mat == 0)      { src = qkv_w + 512 * 512;  dst = bufX; }
        else if (mat == 1) { src = qkv_w;              dst = bufY; }
        else               { src = qkv_w + 1024 * 512; dst = bufY + 262144; }
#pragma unroll
        for (int rr = 0; rr < 4; ++rr) {
            int sr = rr * 16 + (tid >> 4);
            int sc = (tid & 15) * 4;
            float4 v = *(const float4*)(src + (size_t)(c0 + sr) * 512 + r0 + sc);
            T[sc][sr] = v.x; T[sc + 1][sr] = v.y; T[sc + 2][sr] = v.z; T[sc + 3][sr] = v.w;
        }
        __syncthreads();
#pragma unroll
        for (int rr = 0; rr < 4; ++rr) {
            int dr = rr * 16 + (tid >> 4);
            int dc = (tid & 15) * 4;
            short4v o;
            o[0] = (short)f2bf(T[dr][dc]);     o[1] = (short)f2bf(T[dr][dc + 1]);
            o[2] = (short)f2bf(T[dr][dc + 2]); o[3] = (short)f2bf(T[dr][dc + 3]);
            *(short4v*)(dst + (size_t)(r0 + dr) * 512 + c0 + dc) = o;
        }
    } else if (blk < 256) {
        unsigned short* wp = bufX + 262144;
#pragma unroll
        for (int t = 0; t < 4; ++t) {
            int i = (blk - 192) * 4096 + t * 1024 + tid * 4;
            float4 v = *(const float4*)(proj_w + i);
            short4v o;
            o[0] = (short)f2bf(v.x); o[1] = (short)f2bf(v.y);
            o[2] = (short)f2bf(v.z); o[3] = (short)f2bf(v.w);
            *(short4v*)(wp + i) = o;
        }
    } else if (blk < 264) {
        int sub = blk - 256;
        int j = (sub & 1) * 256 + tid;
        int o0 = (sub >> 1) * 128;
        float acc = 0.f;
#pragma unroll 8
        for (int oo = 0; oo < 128; ++oo) {
            int o = o0 + oo;
            acc += qkv_b[o] * qkv_w[(size_t)(512 + o) * 512 + j];
        }
        atomicAdd(&bqWk[j], acc);
    } else {
        int wv = tid >> 6, lane = tid & 63;
        int c = (blk - 264) * 4 + wv;
        float s = 0.f;
#pragma unroll
        for (int t = 0; t < 8; ++t)
            s += proj_w[(size_t)c * 512 + t * 64 + lane] * qkv_b[1024 + t * 64 + lane];
        for (int off = 32; off > 0; off >>= 1) s += __shfl_down(s, off);
        if (lane == 0) biasvp[c] = s;
    }
}

// ---------------------------------------------------------------------------
// Old-style 2-phase NT GEMM, kept only for the tiny step-3 weight GEMMs.
// ---------------------------------------------------------------------------
template<int BIAS_MODE, bool OUT_BF16, bool RESID, bool SWIZ, int KTOT>
__global__ __launch_bounds__(256)
void mfma_gemm(const unsigned short* __restrict__ A, const unsigned short* __restrict__ Bm,
               const float* __restrict__ bias, const float* __restrict__ resid,
               void* __restrict__ Yv,
               int lda, int ldb, int ldy,
               size_t sA, size_t sB, size_t sY, size_t sR, float alpha,
               int ntsh, int nxsh)
{
    __shared__ unsigned short As[2 * 128 * 32];
    __shared__ unsigned short Bs[2 * 128 * 32];
    int bx, by, bz;
    if (SWIZ) {
        int lin = blockIdx.x;
        int xcd = lin & 7, sup = lin >> 3;
        bz = xcd + ((sup >> ntsh) << 3);
        int tile = sup & ((1 << ntsh) - 1);
        bx = tile & ((1 << nxsh) - 1);
        by = tile >> nxsh;
    } else { bx = blockIdx.x; by = blockIdx.y; bz = blockIdx.z; }

    const unsigned short* Ab = A  + (size_t)bz * sA;
    const unsigned short* Bb = Bm + (size_t)bz * sB;
    const int tid = threadIdx.x, wave = tid >> 6, lane = tid & 63;
    const int m0 = by * 128, n0 = bx * 128;
    const int wr = wave >> 1, wc = wave & 1, lr = lane & 15, kq = lane >> 4;
    const int row0 = tid >> 2, kc0 = (tid & 3) << 3;

    floatx4 acc[4][4] = {};

    for (int k0 = 0; k0 < KTOT; k0 += 64) {
        __syncthreads();
#pragma unroll
        for (int kk = 0; kk < 2; ++kk) {
#pragma unroll
            for (int r = 0; r < 2; ++r) {
                const unsigned short* ga = Ab + (size_t)(m0 + r * 64 + row0) * lda + k0 + kk * 32 + kc0;
                __builtin_amdgcn_global_load_lds(
                    (const __attribute__((address_space(1))) void*)ga,
                    (__attribute__((address_space(3))) void*)(As + kk * 4096 + (r * 256 + wave * 64) * 8),
                    16, 0, 0);
                const unsigned short* gb = Bb + (size_t)(n0 + r * 64 + row0) * ldb + k0 + kk * 32 + kc0;
                __builtin_amdgcn_global_load_lds(
                    (const __attribute__((address_space(1))) void*)gb,
                    (__attribute__((address_space(3))) void*)(Bs + kk * 4096 + (r * 256 + wave * 64) * 8),
                    16, 0, 0);
            }
        }
        __syncthreads();

#pragma unroll
        for (int kk = 0; kk < 2; ++kk) {
            short8 af[4], bfr[4];
#pragma unroll
            for (int i = 0; i < 4; ++i)
                af[i] = *(const short8*)&As[kk * 4096 + (wr * 64 + i * 16 + lr) * 32 + kq * 8];
#pragma unroll
            for (int j = 0; j < 4; ++j)
                bfr[j] = *(const short8*)&Bs[kk * 4096 + (wc * 64 + j * 16 + lr) * 32 + kq * 8];
#pragma unroll
            for (int i = 0; i < 4; ++i)
#pragma unroll
                for (int j = 0; j < 4; ++j)
                    acc[i][j] = __builtin_amdgcn_mfma_f32_16x16x32_bf16(af[i], bfr[j], acc[i][j], 0, 0, 0);
        }
    }

    const size_t ybase = (size_t)bz * sY;
    const size_t rbase = (size_t)bz * sR;
#pragma unroll
    for (int i = 0; i < 4; ++i) {
#pragma unroll
        for (int r = 0; r < 4; ++r) {
            int m = m0 + wr * 64 + i * 16 + kq * 4 + r;
            float bm = (BIAS_MODE == 1) ? bias[m] : 0.f;
#pragma unroll
            for (int j = 0; j < 4; ++j) {
                int n = n0 + wc * 64 + j * 16 + lr;
                float vv = acc[i][j][r] * alpha + bm;
                if (BIAS_MODE == 2) vv += bias[n];
                if (RESID) vv += resid[rbase + (size_t)m * ldy + n];
                if (OUT_BF16)
                    ((__hip_bfloat16*)Yv)[ybase + (size_t)m * ldy + n] = __float2bfloat16(vv);
                else
                    ((float*)Yv)[ybase + (size_t)m * ldy + n] = vv;
            }
        }
    }
}

// ---------------------------------------------------------------------------
// 8-phase 128(M)x256(N) NT GEMM (T2+T3+T4+T5), BK=64, 8 waves (2M x 4N),
// per-wave 64x64 output (acc[4][4]). 512 threads, 96 KiB LDS, 1 block/CU.
//
// LDS: A [2buf][128][128B] @asb (32 KiB); B [2buf][2half][128][128B] @bsb.
// Slot lifetimes (audited):
//   A(buf): ds-read in ph0 (i=0,1) and ph2 (i=2,3) -> stage A(t+1) in ph0
//     targets buf^1 (tile t-1's A, last read at t-1 ph2). Safe.
//   B(buf) halves: ds-read in ph0 (jn=0,1) and ph1 (jn=2,3); last read ph1 ->
//     stage B0(t+2) in ph2, B1(t+2) in ph3. Safe.
// Per-iter stages: A(t+1)[ph0], B0(t+2)[ph2], B1(t+2)[ph3] = 6 loads.
// End-of-iter wait: 4 loads younger than A(t+1) -> vmcnt(4) proves A(t+1)
// and all older (B halves of t+1) landed. Drain vmcnt(0) for t >= NT-2.
// Phase order is gray-code so one operand group stays register-resident.
// ---------------------------------------------------------------------------
template<int BIAS_MODE, bool OUT_BF16, bool RESID, bool SWIZ, int KTOT>
__global__ __launch_bounds__(512)
void gemm8ph(const unsigned short* __restrict__ A, const unsigned short* __restrict__ Bm,
             const float* __restrict__ bias, const float* __restrict__ resid,
             void* __restrict__ Yv,
             int lda, int ldb, int ldy,
             size_t sA, size_t sB, size_t sY, size_t sR, float alpha,
             int ntsh, int nxsh)
{
    __shared__ __align__(16) char lds[98304];
    char* asb = lds;            // A: [2 buf][128][128B]
    char* bsb = lds + 32768;    // B: [2 buf][2 half][128][128B]

    int bx, by, bz;
    if (SWIZ) {
        int lin = blockIdx.x;
        int xcd = lin & 7, sup = lin >> 3;
        bz = xcd + ((sup >> ntsh) << 3);
        int tile = sup & ((1 << ntsh) - 1);
        bx = tile & ((1 << nxsh) - 1);
        by = tile >> nxsh;
    } else { bx = blockIdx.x; by = blockIdx.y; bz = blockIdx.z; }

    const unsigned short* Ab = A  + (size_t)bz * sA;
    const unsigned short* Bb = Bm + (size_t)bz * sB;
    const int tid = threadIdx.x, wave = tid >> 6, lane = tid & 63;
    const int m0 = by * 128, n0 = bx * 256;
    const int wr = wave >> 2, wc = wave & 3;   // 2(M) x 4(N) wave grid
    const int lr = lane & 15, kq = lane >> 4;
    const int swz = (lr & 7) << 4;

    floatx4 acc[4][4] = {};
    short8 aF[2][2], bF[2][2][2];

    // stage 128 rows x 64 k (16 KiB): 2 x global_load_lds(16B) per thread.
    // LDS dest linear; global source pre-swizzled (inverse of read XOR).
    auto stage = [&](const unsigned short* __restrict__ G, int ld, int grow,
                     int t, char* dstbase) {
#pragma unroll
        for (int c = 0; c < 2; ++c) {
            int x = c * 8192 + tid * 16;
            int row = x >> 7;
            int colb = (x & 127) ^ ((row & 7) << 4);
            const unsigned short* ga = G + (size_t)(grow + row) * ld + t * 64 + (colb >> 1);
            char* ldst = dstbase + c * 8192 + wave * 1024;
            __builtin_amdgcn_global_load_lds(
                (const __attribute__((address_space(1))) void*)ga,
                (__attribute__((address_space(3))) void*)ldst, 16, 0, 0);
        }
    };
    auto rdA = [&](int buf, int i, int kk) {
        int byte = buf * 16384 + (wr * 64 + i * 16 + lr) * 128
                 + ((kk * 64 + kq * 16) ^ swz);
        return *(const short8*)(asb + byte);
    };
    auto rdB = [&](int buf, int jn, int kk) {
        int row = wc * 64 + jn * 16 + lr;
        int byte = buf * 32768 + (row >> 7) * 16384 + (row & 127) * 128
                 + ((kk * 64 + kq * 16) ^ swz);
        return *(const short8*)(bsb + byte);
    };

    // prologue: tile0 (A,B0,B1) + tile1 (B0,B1); A(1) comes in iter0 ph0.
    stage(Ab, lda, m0,       0, asb);
    stage(Bb, ldb, n0,       0, bsb);
    stage(Bb, ldb, n0 + 128, 0, bsb + 16384);
    stage(Bb, ldb, n0,       1, bsb + 32768);
    stage(Bb, ldb, n0 + 128, 1, bsb + 32768 + 16384);
    asm volatile("s_waitcnt vmcnt(4)" ::: "memory");
    __builtin_amdgcn_s_barrier();

    constexpr int NT = KTOT / 64;
    for (int t = 0; t < NT; ++t) {
        const int buf = t & 1;
        // ---- phase 0: (i=0..1, jn=0..1); stage A(t+1) -> buf^1
#pragma unroll
        for (int ii = 0; ii < 2; ++ii) { aF[ii][0] = rdA(buf, ii, 0); aF[ii][1] = rdA(buf, ii, 1); }
#pragma unroll
        for (int jj = 0; jj < 2; ++jj) { bF[0][jj][0] = rdB(buf, jj, 0); bF[0][jj][1] = rdB(buf, jj, 1); }
        if (t < NT - 1) stage(Ab, lda, m0, t + 1, asb + ((t + 1) & 1) * 16384);
        __builtin_amdgcn_s_barrier();
        asm volatile("s_waitcnt lgkmcnt(0)" ::: "memory");
        __builtin_amdgcn_s_setprio(1);
#pragma unroll
        for (int ii = 0; ii < 2; ++ii)
#pragma unroll
            for (int jj = 0; jj < 2; ++jj)
#pragma unroll
                for (int kk = 0; kk < 2; ++kk)
                    acc[ii][jj] = __builtin_amdgcn_mfma_f32_16x16x32_bf16(aF[ii][kk], bF[0][jj][kk], acc[ii][jj], 0, 0, 0);
        __builtin_amdgcn_s_setprio(0);
        __builtin_amdgcn_s_barrier();
        // ---- phase 1: (i=0..1, jn=2..3); no stage
#pragma unroll
        for (int jj = 0; jj < 2; ++jj) { bF[1][jj][0] = rdB(buf, 2 + jj, 0); bF[1][jj][1] = rdB(buf, 2 + jj, 1); }
        __builtin_amdgcn_s_barrier();
        asm volatile("s_waitcnt lgkmcnt(0)" ::: "memory");
        __builtin_amdgcn_s_setprio(1);
#pragma unroll
        for (int ii = 0; ii < 2; ++ii)
#pragma unroll
            for (int jj = 0; jj < 2; ++jj)
#pragma unroll
                for (int kk = 0; kk < 2; ++kk)
                    acc[ii][2 + jj] = __builtin_amdgcn_mfma_f32_16x16x32_bf16(aF[ii][kk], bF[1][jj][kk], acc[ii][2 + jj], 0, 0, 0);
        __builtin_amdgcn_s_setprio(0);
        __builtin_amdgcn_s_barrier();
        // ---- phase 2: (i=2..3, jn=2..3); stage B0(t+2) (B last read was ph1)
#pragma unroll
        for (int ii = 0; ii < 2; ++ii) { aF[ii][0] = rdA(buf, 2 + ii, 0); aF[ii][1] = rdA(buf, 2 + ii, 1); }
        if (t < NT - 2) stage(Bb, ldb, n0, t + 2, bsb + buf * 32768);
        __builtin_amdgcn_s_barrier();
        asm volatile("s_waitcnt lgkmcnt(0)" ::: "memory");
        __builtin_amdgcn_s_setprio(1);
#pragma unroll
        for (int ii = 0; ii < 2; ++ii)
#pragma unroll
            for (int jj = 0; jj < 2; ++jj)
#pragma unroll
                for (int kk = 0; kk < 2; ++kk)
                    acc[2 + ii][2 + jj] = __builtin_amdgcn_mfma_f32_16x16x32_bf16(aF[ii][kk], bF[1][jj][kk], acc[2 + ii][2 + jj], 0, 0, 0);
        __builtin_amdgcn_s_setprio(0);
        __builtin_amdgcn_s_barrier();
        // ---- phase 3: (i=2..3, jn=0..1), all reg-resident; stage B1(t+2);
        //      K-tile boundary: counted vmcnt, drain only in the tail.
        if (t < NT - 2) stage(Bb, ldb, n0 + 128, t + 2, bsb + buf * 32768 + 16384);
        __builtin_amdgcn_s_setprio(1);
#pragma unroll
        for (int ii = 0; ii < 2; ++ii)
#pragma unroll
            for (int jj = 0; jj < 2; ++jj)
#pragma unroll
                for (int kk = 0; kk < 2; ++kk)
                    acc[2 + ii][jj] = __builtin_amdgcn_mfma_f32_16x16x32_bf16(aF[ii][kk], bF[0][jj][kk], acc[2 + ii][jj], 0, 0, 0);
        __builtin_amdgcn_s_setprio(0);
        if (t < NT - 2) { asm volatile("s_waitcnt vmcnt(4)" ::: "memory"); }
        else            { asm volatile("s_waitcnt vmcnt(0)" ::: "memory"); }
        __builtin_amdgcn_s_barrier();
    }

    const size_t ybase = (size_t)bz * sY;
    const size_t rbase = (size_t)bz * sR;
#pragma unroll
    for (int i = 0; i < 4; ++i) {
#pragma unroll
        for (int r = 0; r < 4; ++r) {
            int m = m0 + wr * 64 + i * 16 + kq * 4 + r;
            float bm = (BIAS_MODE == 1) ? bias[m] : 0.f;
#pragma unroll
            for (int j = 0; j < 4; ++j) {
                int n = n0 + wc * 64 + j * 16 + lr;
                float vv = acc[i][j][r] * alpha + bm;
                if (BIAS_MODE == 2) vv += bias[n];
                if (RESID) vv += resid[rbase + (size_t)m * ldy + n];
                if (OUT_BF16)
                    ((__hip_bfloat16*)Yv)[ybase + (size_t)m * ldy + n] = __float2bfloat16(vv);
                else
                    ((float*)Yv)[ybase + (size_t)m * ldy + n] = vv;
            }
        }
    }
}

// ---------------------------------------------------------------------------
// Scores^T + fused 32-key-chunk softmax + transposed P write. (verified r2)
// ---------------------------------------------------------------------------
__global__ __launch_bounds__(512)
void scores_softmax8(const unsigned short* __restrict__ A,   // xnT (keys)
                     const unsigned short* __restrict__ Bm,  // u (queries)
                     unsigned short* __restrict__ P)
{
    __shared__ __align__(16) unsigned short lds[65536];   // 128 KiB
    char* asb = (char*)lds;            // A: [2 buf][2 half][128 rows][128 B]
    char* bsb = (char*)lds + 65536;    // B: same

    const int bid = blockIdx.x;
    const int bz = bid >> 4, t16 = bid & 15;
    const int by = t16 >> 2, bx = t16 & 3;
    const int m0 = by << 8, n0 = bx << 8;      // m = key, n = sq

    const size_t sAB = (size_t)S_ * 512;
    const unsigned short* Ab = A  + (size_t)bz * sAB;
    const unsigned short* Bb = Bm + (size_t)bz * sAB;

    const int tid = threadIdx.x, wave = tid >> 6, lane = tid & 63;
    const int wr = wave >> 2, wc = wave & 3;   // 2 x 4 wave grid
    const int lr = lane & 15, kq = lane >> 4;
    const int swz = (lr & 7) << 4;

    floatx4 acc[8][4] = {};
    short8 aF[4][2], bF[2][2][2];

    auto stage = [&](const unsigned short* __restrict__ G, int row0, int t,
                     char* base, int buf, int half) {
#pragma unroll
        for (int c = 0; c < 2; ++c) {
            int x = c * 8192 + tid * 16;
            int row = x >> 7;
            int colb = (x & 127) ^ ((row & 7) << 4);
            const unsigned short* ga = G + (((size_t)(row0 + row)) << 9) + (t << 6) + (colb >> 1);
            char* ldst = base + buf * 32768 + half * 16384 + c * 8192 + wave * 1024;
            __builtin_amdgcn_global_load_lds(
                (const __attribute__((address_space(1))) void*)ga,
                (__attribute__((address_space(3))) void*)ldst, 16, 0, 0);
        }
    };
    auto rdA = [&](int buf, int mh, int ii, int kk) {
        int byte = buf * 32768 + wr * 16384 + (mh * 64 + ii * 16 + lr) * 128
                 + ((kk * 64 + kq * 16) ^ swz);
        return *(const short8*)(asb + byte);
    };
    auto rdB = [&](int buf, int nh, int jj, int kk) {
        int trow = wc * 64 + (nh * 2 + jj) * 16 + lr;
        int byte = buf * 32768 + (trow >> 7) * 16384 + (trow & 127) * 128
                 + ((kk * 64 + kq * 16) ^ swz);
        return *(const short8*)(bsb + byte);
    };

    stage(Ab, m0,       0, asb, 0, 0);
    stage(Bb, n0,       0, bsb, 0, 0);
    stage(Bb, n0 + 128, 0, bsb, 0, 1);
    stage(Ab, m0 + 128, 0, asb, 0, 1);
    stage(Ab, m0,       1, asb, 1, 0);
    stage(Bb, n0,       1, bsb, 1, 0);
    stage(Bb, n0 + 128, 1, bsb, 1, 1);
    asm volatile("s_waitcnt vmcnt(6)" ::: "memory");
    __builtin_amdgcn_s_barrier();

    for (int t = 0; t < 8; ++t) {
        const int buf = t & 1;
        // ---- phase 0: quad (mh=0, nh=0); stage A1(t+1) -> buf^1 (safe)
#pragma unroll
        for (int ii = 0; ii < 4; ++ii) { aF[ii][0] = rdA(buf, 0, ii, 0); aF[ii][1] = rdA(buf, 0, ii, 1); }
#pragma unroll
        for (int jj = 0; jj < 2; ++jj) { bF[0][jj][0] = rdB(buf, 0, jj, 0); bF[0][jj][1] = rdB(buf, 0, jj, 1); }
        if (t < 7) stage(Ab, m0 + 128, t + 1, asb, (t + 1) & 1, 1);
        __builtin_amdgcn_s_barrier();
        asm volatile("s_waitcnt lgkmcnt(0)" ::: "memory");
        __builtin_amdgcn_s_setprio(1);
#pragma unroll
        for (int ii = 0; ii < 4; ++ii)
#pragma unroll
            for (int jj = 0; jj < 2; ++jj)
#pragma unroll
                for (int kk = 0; kk < 2; ++kk)
                    acc[ii][jj] = __builtin_amdgcn_mfma_f32_16x16x32_bf16(aF[ii][kk], bF[0][jj][kk], acc[ii][jj], 0, 0, 0);
        __builtin_amdgcn_s_setprio(0);
        __builtin_amdgcn_s_barrier();
        // ---- phase 1: quad (0,1); NO stage (A half0 still live until ph2)
#pragma unroll
        for (int jj = 0; jj < 2; ++jj) { bF[1][jj][0] = rdB(buf, 1, jj, 0); bF[1][jj][1] = rdB(buf, 1, jj, 1); }
        __builtin_amdgcn_s_barrier();
        asm volatile("s_waitcnt lgkmcnt(0)" ::: "memory");
        __builtin_amdgcn_s_setprio(1);
#pragma unroll
        for (int ii = 0; ii < 4; ++ii)
#pragma unroll
            for (int jj = 0; jj < 2; ++jj)
#pragma unroll
                for (int kk = 0; kk < 2; ++kk)
                    acc[ii][2 + jj] = __builtin_amdgcn_mfma_f32_16x16x32_bf16(aF[ii][kk], bF[1][jj][kk], acc[ii][2 + jj], 0, 0, 0);
        __builtin_amdgcn_s_setprio(0);
        __builtin_amdgcn_s_barrier();
        // ---- phase 2: quad (1,1); stage B0(t+2) (B half0 reads ended ph1)
#pragma unroll
        for (int ii = 0; ii < 4; ++ii) { aF[ii][0] = rdA(buf, 1, ii, 0); aF[ii][1] = rdA(buf, 1, ii, 1); }
        if (t < 6) stage(Bb, n0, t + 2, bsb, buf, 0);
        __builtin_amdgcn_s_barrier();
        asm volatile("s_waitcnt lgkmcnt(0)" ::: "memory");
        __builtin_amdgcn_s_setprio(1);
#pragma unroll
        for (int ii = 0; ii < 4; ++ii)
#pragma unroll
            for (int jj = 0; jj < 2; ++jj)
#pragma unroll
                for (int kk = 0; kk < 2; ++kk)
                    acc[4 + ii][2 + jj] = __builtin_amdgcn_mfma_f32_16x16x32_bf16(aF[ii][kk], bF[1][jj][kk], acc[4 + ii][2 + jj], 0, 0, 0);
        __builtin_amdgcn_s_setprio(0);
        __builtin_amdgcn_s_barrier();
        // ---- phase 3: quad (1,0), reg-resident; stage A0(t+2)+B1(t+2)
        if (t < 6) {
            stage(Ab, m0,       t + 2, asb, buf, 0);
            stage(Bb, n0 + 128, t + 2, bsb, buf, 1);
        }
        __builtin_amdgcn_s_setprio(1);
#pragma unroll
        for (int ii = 0; ii < 4; ++ii)
#pragma unroll
            for (int jj = 0; jj < 2; ++jj)
#pragma unroll
                for (int kk = 0; kk < 2; ++kk)
                    acc[4 + ii][jj] = __builtin_amdgcn_mfma_f32_16x16x32_bf16(aF[ii][kk], bF[0][jj][kk], acc[4 + ii][jj], 0, 0, 0);
        __builtin_amdgcn_s_setprio(0);
        if (t < 6) { asm volatile("s_waitcnt vmcnt(6)" ::: "memory"); }
        else       { asm volatile("s_waitcnt vmcnt(0)" ::: "memory"); }
        __builtin_amdgcn_s_barrier();
    }

    // softmax over 32-key chunks; write P^T tile into reused LDS (swizzled)
#pragma unroll
    for (int j = 0; j < 4; ++j) {
        int sqc = wc * 64 + j * 16 + lr;
        int srow = sqc * 512;
        int sxor = (sqc & 7) << 4;
#pragma unroll
        for (int h = 0; h < 4; ++h) {
            float v0[4], v1[4];
            float mx = -1e30f;
#pragma unroll
            for (int r = 0; r < 4; ++r) {
                v0[r] = acc[2 * h][j][r]     * 0.125f;
                v1[r] = acc[2 * h + 1][j][r] * 0.125f;
                mx = fmaxf(mx, fmaxf(v0[r], v1[r]));
            }
            mx = fmaxf(mx, __shfl_xor(mx, 16));
            mx = fmaxf(mx, __shfl_xor(mx, 32));
            float sm = 0.f;
#pragma unroll
            for (int r = 0; r < 4; ++r) {
                v0[r] = __expf(v0[r] - mx);
                v1[r] = __expf(v1[r] - mx);
                sm += v0[r] + v1[r];
            }
            sm += __shfl_xor(sm, 16);
            sm += __shfl_xor(sm, 32);
            float inv = 1.f / sm;
            short4v p0, p1;
#pragma unroll
            for (int r = 0; r < 4; ++r) {
                p0[r] = (short)f2bf(v0[r] * inv);
                p1[r] = (short)f2bf(v1[r] * inv);
            }
            int kb = (wr * 128 + h * 32 + kq * 4) * 2;
            *(short4v*)(asb + ((srow + kb) ^ sxor))      = p0;
            *(short4v*)(asb + ((srow + kb + 32) ^ sxor)) = p1;
        }
    }
    __syncthreads();

    const size_t pbase = ((size_t)bz << 20) + (size_t)n0 * 1024 + m0;
#pragma unroll
    for (int it = 0; it < 16; ++it) {
        int row = wave * 32 + it * 2 + (lane >> 5);
        int colb = (lane & 31) << 4;
        short8 v = *(const short8*)(asb + ((row * 512 + colb) ^ ((row & 7) << 4)));
        *(short8*)(P + pbase + (size_t)row * 1024 + (colb >> 1)) = v;
    }
}

// ---------------------------------------------------------------------------
extern "C" void kernel_launch(void* const* d_in, const int* in_sizes, int n_in,
                              void* d_out, int out_size, void* d_ws, size_t ws_size,
                              hipStream_t stream) {
    const float* x     = (const float*)d_in[0];
    const float* gn_w  = (const float*)d_in[1];
    const float* gn_b  = (const float*)d_in[2];
    const float* qkv_w = (const float*)d_in[3];
    const float* qkv_b = (const float*)d_in[4];
    const float* pr_w  = (const float*)d_in[5];
    const float* pr_b  = (const float*)d_in[6];
    float* out = (float*)d_out;

    char* w = (char*)d_ws;
    __hip_bfloat16* xnT  = (__hip_bfloat16*)w;                     // 16 MiB [16][1024][512]
    __hip_bfloat16* u    = (__hip_bfloat16*)(w + (16u << 20));     // 16 MiB [16][1024][512]
    __hip_bfloat16* Vp   = (__hip_bfloat16*)(w + (32u << 20));     // 16 MiB [16][512][1024]
    __hip_bfloat16* P    = (__hip_bfloat16*)(w + (48u << 20));     // 32 MiB [16][1024][1024]
    unsigned short* bufX = (unsigned short*)(w + (80u << 20));     // 1 MiB [WkT | wp_bf]
    unsigned short* bufY = (unsigned short*)(w + (81u << 20));     // 1 MiB [WqT | WvT]
    unsigned short* bufZ = (unsigned short*)(w + (82u << 20));     // 1 MiB [MT | W']
    float*          bqWk = (float*)(w + (83u << 20));              // 2 KiB
    float*          bvp  = (float*)(w + (83u << 20) + 4096);       // 2 KiB

    // 0) zero the bqWk accumulator (atomics target)
    hipMemsetAsync(bqWk, 0, 512 * sizeof(float), stream);

    // 1) prep: transposes -> bf16, wp convert, parallel bias matvecs
    prep_kernel<<<392, 256, 0, stream>>>(qkv_w, pr_w, qkv_b, bufX, bufY, bqWk, bvp);

    // 2) fused GroupNorm -> xnT
    gn_fused_kernel<<<B_ * NGRP, 256, 0, stream>>>(x, gn_w, gn_b, xnT);

    // 3) MT = WkT . WqT^T  (z=0)  and  W' = Wp . WvT^T  (z=1): 512x512x512 NT
    mfma_gemm<0, true, false, false, 512><<<dim3(4, 4, 2), 256, 0, stream>>>(
        bufX, bufY, nullptr, nullptr, bufZ,
        512, 512, 512, 262144, 262144, 262144, 0, 1.f, 0, 0);

    // 4) u = xnT . MT^T + bqWk[n]   M=16384, N=512, K=512  (8-phase 128x256)
    gemm8ph<2, true, false, false, 512><<<dim3(2, 128, 1), 512, 0, stream>>>(
        (const unsigned short*)xnT, bufZ, bqWk, nullptr, u,
        512, 512, 512, 0, 0, 0, 0, 1.f, 0, 0);

    // 5) V' = W' . xnT^T + bvp[m]   batched: M=512(c), N=1024(key), K=512
    gemm8ph<1, true, false, true, 512><<<256, 512, 0, stream>>>(
        bufZ + 262144, (const unsigned short*)xnT, bvp, nullptr, Vp,
        512, 512, 1024, 0, (size_t)S_ * 512, (size_t)512 * S_, 0, 1.f, 4, 2);

    // 6) scores^T + fused softmax + transpose -> P[sq][key]  (8-phase 256^2)
    scores_softmax8<<<256, 512, 0, stream>>>(
        (const unsigned short*)xnT, (const unsigned short*)u, (unsigned short*)P);

    // 7) out = V' . P^T + pr_b[m] + x   batched: M=512(c), N=1024(sq), K=1024
    gemm8ph<1, false, true, true, 1024><<<256, 512, 0, stream>>>(
        (const unsigned short*)Vp, (const unsigned short*)P, pr_b, x, out,
        1024, 1024, 1024, (size_t)512 * S_, (size_t)S_ * S_, (size_t)512 * S_,
        (size_t)512 * S_, 1.f, 4, 2);
}

// Round 5
// 196.415 us; speedup vs baseline: 1.1050x; 1.0069x over previous
//
#include <hip/hip_runtime.h>
#include <hip/hip_bf16.h>

#define B_    16
#define C_    512
#define S_    1024      // H*W
#define NGRP  32
#define CPG   16

typedef __attribute__((ext_vector_type(8))) short  short8;
typedef __attribute__((ext_vector_type(4))) short  short4v;
typedef __attribute__((ext_vector_type(4))) float  floatx4;

__device__ __forceinline__ unsigned short f2bf(float f) {
    __hip_bfloat16 h = __float2bfloat16(f);
    unsigned short u;
    __builtin_memcpy(&u, &h, 2);
    return u;
}

// ---------------------------------------------------------------------------
// Prep: weight transposes->bf16, wp convert, parallel bias matvecs.
// ---------------------------------------------------------------------------
__global__ __launch_bounds__(256)
void prep_kernel(const float* __restrict__ qkv_w, const float* __restrict__ proj_w,
                 const float* __restrict__ qkv_b,
                 unsigned short* __restrict__ bufX,   // [WkT | wp_bf]
                 unsigned short* __restrict__ bufY,   // [WqT | WvT]
                 float* __restrict__ bqWk, float* __restrict__ biasvp)
{
    int blk = blockIdx.x;
    int tid = threadIdx.x;
    if (blk < 192) {
        __shared__ float T[64][65];
        int mat = blk >> 6, tile = blk & 63;
        int r0 = (tile >> 3) * 64, c0 = (tile & 7) * 64;  // dst[r0+i][c0+j] = src[c0+j][r0+i]
        const float* src; unsigned short* dst;
        if (mat == 0)      { src = qkv_w + 512 * 512;  dst = bufX; }
        else if (mat == 1) { src = qkv_w;              dst = bufY; }
        else               { src = qkv_w + 1024 * 512; dst = bufY + 262144; }
#pragma unroll
        for (int rr = 0; rr < 4; ++rr) {
            int sr = rr * 16 + (tid >> 4);
            int sc = (tid & 15) * 4;
            float4 v = *(const float4*)(src + (size_t)(c0 + sr) * 512 + r0 + sc);
            T[sc][sr] = v.x; T[sc + 1][sr] = v.y; T[sc + 2][sr] = v.z; T[sc + 3][sr] = v.w;
        }
        __syncthreads();
#pragma unroll
        for (int rr = 0; rr < 4; ++rr) {
            int dr = rr * 16 + (tid >> 4);
            int dc = (tid & 15) * 4;
            short4v o;
            o[0] = (short)f2bf(T[dr][dc]);     o[1] = (short)f2bf(T[dr][dc + 1]);
            o[2] = (short)f2bf(T[dr][dc + 2]); o[3] = (short)f2bf(T[dr][dc + 3]);
            *(short4v*)(dst + (size_t)(r0 + dr) * 512 + c0 + dc) = o;
        }
    } else if (blk < 256) {
        unsigned short* wp = bufX + 262144;
#pragma unroll
        for (int t = 0; t < 4; ++t) {
            int i = (blk - 192) * 4096 + t * 1024 + tid * 4;
            float4 v = *(const float4*)(proj_w + i);
            short4v o;
            o[0] = (short)f2bf(v.x); o[1] = (short)f2bf(v.y);
            o[2] = (short)f2bf(v.z); o[3] = (short)f2bf(v.w);
            *(short4v*)(wp + i) = o;
        }
    } else if (blk < 264) {
        int sub = blk - 256;
        int j = (sub & 1) * 256 + tid;
        int o0 = (sub >> 1) * 128;
        float acc = 0.f;
#pragma unroll 8
        for (int oo = 0; oo < 128; ++oo) {
            int o = o0 + oo;
            acc += qkv_b[o] * qkv_w[(size_t)(512 + o) * 512 + j];
        }
        atomicAdd(&bqWk[j], acc);
    } else {
        int wv = tid >> 6, lane = tid & 63;
        int c = (blk - 264) * 4 + wv;
        float s = 0.f;
#pragma unroll
        for (int t = 0; t < 8; ++t)
            s += proj_w[(size_t)c * 512 + t * 64 + lane] * qkv_b[1024 + t * 64 + lane];
        for (int off = 32; off > 0; off >>= 1) s += __shfl_down(s, off);
        if (lane == 0) biasvp[c] = s;
    }
}

// ---------------------------------------------------------------------------
// Merge 1: blocks 0..511 = fused GroupNorm -> xnT; blocks 512..543 = the two
// 512x512x512 weight GEMMs (2-phase 128^2), hidden under gn's memory time.
// Both only depend on prep (previous launch). 256 threads.
// ---------------------------------------------------------------------------
__global__ __launch_bounds__(256)
void gn_plus_w(const float* __restrict__ x, const float* __restrict__ gnw,
               const float* __restrict__ gnb, __hip_bfloat16* __restrict__ xnT,
               const unsigned short* __restrict__ bufX,
               const unsigned short* __restrict__ bufY,
               unsigned short* __restrict__ bufZ)
{
    __shared__ __align__(16) char smem[32832];   // 32 KiB gemm | 64 B gn-red
    int blk = blockIdx.x;
    int tid = threadIdx.x;

    if (blk < 512) {
        // ---------------- GroupNorm branch (identical math to r2-verified) --
        int b = blk >> 5, g = blk & 31;
        const float4* xp = (const float4*)(x + (size_t)blk * (CPG * S_));
        float4 vv[16];
        float s = 0.f, ss = 0.f;
#pragma unroll
        for (int r = 0; r < 16; ++r) {
            float4 v = xp[r * 256 + tid];
            vv[r] = v;
            s  += v.x + v.y + v.z + v.w;
            ss += v.x*v.x + v.y*v.y + v.z*v.z + v.w*v.w;
        }
        for (int off = 32; off > 0; off >>= 1) {
            s  += __shfl_down(s, off);
            ss += __shfl_down(ss, off);
        }
        float* red = (float*)(smem + 32768);   // [8] : sums | sumsq
        float* msh = (float*)(smem + 32800);   // [2] : mean, inv
        int wid = tid >> 6, lane = tid & 63;
        if (lane == 0) { red[wid] = s; red[4 + wid] = ss; }
        __syncthreads();
        if (tid == 0) {
            float a = 0.f, c = 0.f;
            for (int i = 0; i < 4; ++i) { a += red[i]; c += red[4 + i]; }
            float mean = a / (float)(CPG * S_);
            float var  = c / (float)(CPG * S_) - mean * mean;
            msh[0] = mean;
            msh[1] = rsqrtf(var + 1e-5f);
        }
        __syncthreads();
        float mean = msh[0], inv = msh[1];

        float sc[16], sh[16];
#pragma unroll
        for (int c = 0; c < 16; ++c) {
            float wc = gnw[g * 16 + c];
            sc[c] = inv * wc;
            sh[c] = gnb[g * 16 + c] - mean * inv * wc;
        }
#pragma unroll
        for (int kk = 0; kk < 4; ++kk) {
            unsigned short outp[16];
#pragma unroll
            for (int c = 0; c < 16; ++c) {
                float v = (kk == 0) ? vv[c].x : (kk == 1) ? vv[c].y : (kk == 2) ? vv[c].z : vv[c].w;
                outp[c] = f2bf(v * sc[c] + sh[c]);
            }
            int srow = 4 * tid + kk;
            unsigned short* dst = (unsigned short*)xnT + ((size_t)(b * S_ + srow) * C_ + g * 16);
            *(short8*)dst       = *(short8*)outp;
            *(short8*)(dst + 8) = *(short8*)(outp + 8);
        }
    } else {
        // ---------------- 2-phase 128^2 NT GEMM (s3), params folded ---------
        unsigned short* As = (unsigned short*)smem;          // 2*128*32
        unsigned short* Bs = (unsigned short*)(smem + 16384);
        int id = blk - 512;                 // 0..31
        int bx = id & 3, by = (id >> 2) & 3, bz = id >> 4;
        const unsigned short* Ab = bufX + (size_t)bz * 262144;
        const unsigned short* Bb = bufY + (size_t)bz * 262144;
        __hip_bfloat16* Y = (__hip_bfloat16*)bufZ + (size_t)bz * 262144;
        const int wave = tid >> 6, lane = tid & 63;
        const int m0 = by * 128, n0 = bx * 128;
        const int wr = wave >> 1, wc = wave & 1, lr = lane & 15, kq = lane >> 4;
        const int row0 = tid >> 2, kc0 = (tid & 3) << 3;

        floatx4 acc[4][4] = {};
        for (int k0 = 0; k0 < 512; k0 += 64) {
            __syncthreads();
#pragma unroll
            for (int kk = 0; kk < 2; ++kk) {
#pragma unroll
                for (int r = 0; r < 2; ++r) {
                    const unsigned short* ga = Ab + (size_t)(m0 + r * 64 + row0) * 512 + k0 + kk * 32 + kc0;
                    __builtin_amdgcn_global_load_lds(
                        (const __attribute__((address_space(1))) void*)ga,
                        (__attribute__((address_space(3))) void*)(As + kk * 4096 + (r * 256 + wave * 64) * 8),
                        16, 0, 0);
                    const unsigned short* gb = Bb + (size_t)(n0 + r * 64 + row0) * 512 + k0 + kk * 32 + kc0;
                    __builtin_amdgcn_global_load_lds(
                        (const __attribute__((address_space(1))) void*)gb,
                        (__attribute__((address_space(3))) void*)(Bs + kk * 4096 + (r * 256 + wave * 64) * 8),
                        16, 0, 0);
                }
            }
            __syncthreads();
#pragma unroll
            for (int kk = 0; kk < 2; ++kk) {
                short8 af[4], bfr[4];
#pragma unroll
                for (int i = 0; i < 4; ++i)
                    af[i] = *(const short8*)&As[kk * 4096 + (wr * 64 + i * 16 + lr) * 32 + kq * 8];
#pragma unroll
                for (int j = 0; j < 4; ++j)
                    bfr[j] = *(const short8*)&Bs[kk * 4096 + (wc * 64 + j * 16 + lr) * 32 + kq * 8];
#pragma unroll
                for (int i = 0; i < 4; ++i)
#pragma unroll
                    for (int j = 0; j < 4; ++j)
                        acc[i][j] = __builtin_amdgcn_mfma_f32_16x16x32_bf16(af[i], bfr[j], acc[i][j], 0, 0, 0);
            }
        }
#pragma unroll
        for (int i = 0; i < 4; ++i)
#pragma unroll
            for (int r = 0; r < 4; ++r) {
                int m = m0 + wr * 64 + i * 16 + kq * 4 + r;
#pragma unroll
                for (int j = 0; j < 4; ++j) {
                    int n = n0 + wc * 64 + j * 16 + lr;
                    Y[(size_t)m * 512 + n] = __float2bfloat16(acc[i][j][r]);
                }
            }
    }
}

// ---------------------------------------------------------------------------
// 8-phase 128(M)x256(N) NT GEMM body (T2+T3+T4+T5), BK=64, 8 waves (2M x 4N),
// per-wave 64x64 (acc[4][4]). KTOT=512 (NT=8), bf16 out, no resid, alpha=1.
// Schedule identical to the r4-verified gemm8ph (slot lifetimes audited there).
// ---------------------------------------------------------------------------
template<int BIAS_MODE>
__device__ __forceinline__
void gemm8_body(char* lds, const unsigned short* __restrict__ Ab,
                const unsigned short* __restrict__ Bb,
                const float* __restrict__ bias,
                __hip_bfloat16* __restrict__ Y,
                int lda, int ldb, int ldy, size_t ybase, int m0, int n0)
{
    char* asb = lds;            // A: [2 buf][128][128B]
    char* bsb = lds + 32768;    // B: [2 buf][2 half][128][128B]
    const int tid = threadIdx.x, wave = tid >> 6, lane = tid & 63;
    const int wr = wave >> 2, wc = wave & 3;
    const int lr = lane & 15, kq = lane >> 4;
    const int swz = (lr & 7) << 4;

    floatx4 acc[4][4] = {};
    short8 aF[2][2], bF[2][2][2];

    auto stage = [&](const unsigned short* __restrict__ G, int ld, int grow,
                     int t, char* dstbase) {
#pragma unroll
        for (int c = 0; c < 2; ++c) {
            int x = c * 8192 + tid * 16;
            int row = x >> 7;
            int colb = (x & 127) ^ ((row & 7) << 4);
            const unsigned short* ga = G + (size_t)(grow + row) * ld + t * 64 + (colb >> 1);
            char* ldst = dstbase + c * 8192 + wave * 1024;
            __builtin_amdgcn_global_load_lds(
                (const __attribute__((address_space(1))) void*)ga,
                (__attribute__((address_space(3))) void*)ldst, 16, 0, 0);
        }
    };
    auto rdA = [&](int buf, int i, int kk) {
        int byte = buf * 16384 + (wr * 64 + i * 16 + lr) * 128
                 + ((kk * 64 + kq * 16) ^ swz);
        return *(const short8*)(asb + byte);
    };
    auto rdB = [&](int buf, int jn, int kk) {
        int row = wc * 64 + jn * 16 + lr;
        int byte = buf * 32768 + (row >> 7) * 16384 + (row & 127) * 128
                 + ((kk * 64 + kq * 16) ^ swz);
        return *(const short8*)(bsb + byte);
    };

    stage(Ab, lda, m0,       0, asb);
    stage(Bb, ldb, n0,       0, bsb);
    stage(Bb, ldb, n0 + 128, 0, bsb + 16384);
    stage(Bb, ldb, n0,       1, bsb + 32768);
    stage(Bb, ldb, n0 + 128, 1, bsb + 32768 + 16384);
    asm volatile("s_waitcnt vmcnt(4)" ::: "memory");
    __builtin_amdgcn_s_barrier();

    constexpr int NT = 8;
    for (int t = 0; t < NT; ++t) {
        const int buf = t & 1;
        // phase 0
#pragma unroll
        for (int ii = 0; ii < 2; ++ii) { aF[ii][0] = rdA(buf, ii, 0); aF[ii][1] = rdA(buf, ii, 1); }
#pragma unroll
        for (int jj = 0; jj < 2; ++jj) { bF[0][jj][0] = rdB(buf, jj, 0); bF[0][jj][1] = rdB(buf, jj, 1); }
        if (t < NT - 1) stage(Ab, lda, m0, t + 1, asb + ((t + 1) & 1) * 16384);
        __builtin_amdgcn_s_barrier();
        asm volatile("s_waitcnt lgkmcnt(0)" ::: "memory");
        __builtin_amdgcn_s_setprio(1);
#pragma unroll
        for (int ii = 0; ii < 2; ++ii)
#pragma unroll
            for (int jj = 0; jj < 2; ++jj)
#pragma unroll
                for (int kk = 0; kk < 2; ++kk)
                    acc[ii][jj] = __builtin_amdgcn_mfma_f32_16x16x32_bf16(aF[ii][kk], bF[0][jj][kk], acc[ii][jj], 0, 0, 0);
        __builtin_amdgcn_s_setprio(0);
        __builtin_amdgcn_s_barrier();
        // phase 1
#pragma unroll
        for (int jj = 0; jj < 2; ++jj) { bF[1][jj][0] = rdB(buf, 2 + jj, 0); bF[1][jj][1] = rdB(buf, 2 + jj, 1); }
        __builtin_amdgcn_s_barrier();
        asm volatile("s_waitcnt lgkmcnt(0)" ::: "memory");
        __builtin_amdgcn_s_setprio(1);
#pragma unroll
        for (int ii = 0; ii < 2; ++ii)
#pragma unroll
            for (int jj = 0; jj < 2; ++jj)
#pragma unroll
                for (int kk = 0; kk < 2; ++kk)
                    acc[ii][2 + jj] = __builtin_amdgcn_mfma_f32_16x16x32_bf16(aF[ii][kk], bF[1][jj][kk], acc[ii][2 + jj], 0, 0, 0);
        __builtin_amdgcn_s_setprio(0);
        __builtin_amdgcn_s_barrier();
        // phase 2
#pragma unroll
        for (int ii = 0; ii < 2; ++ii) { aF[ii][0] = rdA(buf, 2 + ii, 0); aF[ii][1] = rdA(buf, 2 + ii, 1); }
        if (t < NT - 2) stage(Bb, ldb, n0, t + 2, bsb + buf * 32768);
        __builtin_amdgcn_s_barrier();
        asm volatile("s_waitcnt lgkmcnt(0)" ::: "memory");
        __builtin_amdgcn_s_setprio(1);
#pragma unroll
        for (int ii = 0; ii < 2; ++ii)
#pragma unroll
            for (int jj = 0; jj < 2; ++jj)
#pragma unroll
                for (int kk = 0; kk < 2; ++kk)
                    acc[2 + ii][2 + jj] = __builtin_amdgcn_mfma_f32_16x16x32_bf16(aF[ii][kk], bF[1][jj][kk], acc[2 + ii][2 + jj], 0, 0, 0);
        __builtin_amdgcn_s_setprio(0);
        __builtin_amdgcn_s_barrier();
        // phase 3
        if (t < NT - 2) stage(Bb, ldb, n0 + 128, t + 2, bsb + buf * 32768 + 16384);
        __builtin_amdgcn_s_setprio(1);
#pragma unroll
        for (int ii = 0; ii < 2; ++ii)
#pragma unroll
            for (int jj = 0; jj < 2; ++jj)
#pragma unroll
                for (int kk = 0; kk < 2; ++kk)
                    acc[2 + ii][jj] = __builtin_amdgcn_mfma_f32_16x16x32_bf16(aF[ii][kk], bF[0][jj][kk], acc[2 + ii][jj], 0, 0, 0);
        __builtin_amdgcn_s_setprio(0);
        if (t < NT - 2) { asm volatile("s_waitcnt vmcnt(4)" ::: "memory"); }
        else            { asm volatile("s_waitcnt vmcnt(0)" ::: "memory"); }
        __builtin_amdgcn_s_barrier();
    }

#pragma unroll
    for (int i = 0; i < 4; ++i)
#pragma unroll
        for (int r = 0; r < 4; ++r) {
            int m = m0 + wr * 64 + i * 16 + kq * 4 + r;
            float bm = (BIAS_MODE == 1) ? bias[m] : 0.f;
#pragma unroll
            for (int j = 0; j < 4; ++j) {
                int n = n0 + wc * 64 + j * 16 + lr;
                float vv = acc[i][j][r] + bm;
                if (BIAS_MODE == 2) vv += bias[n];
                Y[ybase + (size_t)m * ldy + n] = __float2bfloat16(vv);
            }
        }
}

// ---------------------------------------------------------------------------
// Merge 2: blocks 0..255 = u GEMM (s4), 256..511 = V' GEMM (s5). Both depend
// only on xnT + weights; one launch overlaps s4's tail with s5's head.
// ---------------------------------------------------------------------------
__global__ __launch_bounds__(512)
void fused_s45(const unsigned short* __restrict__ xnT,
               const unsigned short* __restrict__ bufZ,
               const float* __restrict__ bqWk, const float* __restrict__ bvp,
               __hip_bfloat16* __restrict__ u, __hip_bfloat16* __restrict__ Vp)
{
    __shared__ __align__(16) char lds[98304];
    int blk = blockIdx.x;
    if (blk < 256) {
        // s4: u = xnT . MT^T + bqWk[n]; M=16384, N=512, K=512
        int by = blk >> 1, bx = blk & 1;
        gemm8_body<2>(lds, xnT, bufZ, bqWk, u,
                      512, 512, 512, 0, by * 128, bx * 256);
    } else {
        // s5: V' = W' . xnT^T + bvp[m]; batched M=512, N=1024, K=512 (XCD swz)
        int lin = blk - 256;
        int xcd = lin & 7, sup = lin >> 3;
        int bz = xcd + ((sup >> 4) << 3);
        int tile = sup & 15;
        int bx = tile & 3, by = tile >> 2;
        gemm8_body<1>(lds, bufZ + 262144, xnT + (size_t)bz * ((size_t)S_ * 512),
                      bvp, Vp,
                      512, 512, 1024, (size_t)bz * 512 * S_, by * 128, bx * 256);
    }
}

// ---------------------------------------------------------------------------
// 8-phase 128x256 NT GEMM standalone (s7: fp32 out + residual, KTOT=1024).
// Schedule identical to r4-verified gemm8ph.
// ---------------------------------------------------------------------------
template<int BIAS_MODE, bool OUT_BF16, bool RESID, bool SWIZ, int KTOT>
__global__ __launch_bounds__(512)
void gemm8ph(const unsigned short* __restrict__ A, const unsigned short* __restrict__ Bm,
             const float* __restrict__ bias, const float* __restrict__ resid,
             void* __restrict__ Yv,
             int lda, int ldb, int ldy,
             size_t sA, size_t sB, size_t sY, size_t sR, float alpha,
             int ntsh, int nxsh)
{
    __shared__ __align__(16) char lds[98304];
    char* asb = lds;
    char* bsb = lds + 32768;

    int bx, by, bz;
    if (SWIZ) {
        int lin = blockIdx.x;
        int xcd = lin & 7, sup = lin >> 3;
        bz = xcd + ((sup >> ntsh) << 3);
        int tile = sup & ((1 << ntsh) - 1);
        bx = tile & ((1 << nxsh) - 1);
        by = tile >> nxsh;
    } else { bx = blockIdx.x; by = blockIdx.y; bz = blockIdx.z; }

    const unsigned short* Ab = A  + (size_t)bz * sA;
    const unsigned short* Bb = Bm + (size_t)bz * sB;
    const int tid = threadIdx.x, wave = tid >> 6, lane = tid & 63;
    const int m0 = by * 128, n0 = bx * 256;
    const int wr = wave >> 2, wc = wave & 3;
    const int lr = lane & 15, kq = lane >> 4;
    const int swz = (lr & 7) << 4;

    floatx4 acc[4][4] = {};
    short8 aF[2][2], bF[2][2][2];

    auto stage = [&](const unsigned short* __restrict__ G, int ld, int grow,
                     int t, char* dstbase) {
#pragma unroll
        for (int c = 0; c < 2; ++c) {
            int x = c * 8192 + tid * 16;
            int row = x >> 7;
            int colb = (x & 127) ^ ((row & 7) << 4);
            const unsigned short* ga = G + (size_t)(grow + row) * ld + t * 64 + (colb >> 1);
            char* ldst = dstbase + c * 8192 + wave * 1024;
            __builtin_amdgcn_global_load_lds(
                (const __attribute__((address_space(1))) void*)ga,
                (__attribute__((address_space(3))) void*)ldst, 16, 0, 0);
        }
    };
    auto rdA = [&](int buf, int i, int kk) {
        int byte = buf * 16384 + (wr * 64 + i * 16 + lr) * 128
                 + ((kk * 64 + kq * 16) ^ swz);
        return *(const short8*)(asb + byte);
    };
    auto rdB = [&](int buf, int jn, int kk) {
        int row = wc * 64 + jn * 16 + lr;
        int byte = buf * 32768 + (row >> 7) * 16384 + (row & 127) * 128
                 + ((kk * 64 + kq * 16) ^ swz);
        return *(const short8*)(bsb + byte);
    };

    stage(Ab, lda, m0,       0, asb);
    stage(Bb, ldb, n0,       0, bsb);
    stage(Bb, ldb, n0 + 128, 0, bsb + 16384);
    stage(Bb, ldb, n0,       1, bsb + 32768);
    stage(Bb, ldb, n0 + 128, 1, bsb + 32768 + 16384);
    asm volatile("s_waitcnt vmcnt(4)" ::: "memory");
    __builtin_amdgcn_s_barrier();

    constexpr int NT = KTOT / 64;
    for (int t = 0; t < NT; ++t) {
        const int buf = t & 1;
#pragma unroll
        for (int ii = 0; ii < 2; ++ii) { aF[ii][0] = rdA(buf, ii, 0); aF[ii][1] = rdA(buf, ii, 1); }
#pragma unroll
        for (int jj = 0; jj < 2; ++jj) { bF[0][jj][0] = rdB(buf, jj, 0); bF[0][jj][1] = rdB(buf, jj, 1); }
        if (t < NT - 1) stage(Ab, lda, m0, t + 1, asb + ((t + 1) & 1) * 16384);
        __builtin_amdgcn_s_barrier();
        asm volatile("s_waitcnt lgkmcnt(0)" ::: "memory");
        __builtin_amdgcn_s_setprio(1);
#pragma unroll
        for (int ii = 0; ii < 2; ++ii)
#pragma unroll
            for (int jj = 0; jj < 2; ++jj)
#pragma unroll
                for (int kk = 0; kk < 2; ++kk)
                    acc[ii][jj] = __builtin_amdgcn_mfma_f32_16x16x32_bf16(aF[ii][kk], bF[0][jj][kk], acc[ii][jj], 0, 0, 0);
        __builtin_amdgcn_s_setprio(0);
        __builtin_amdgcn_s_barrier();
#pragma unroll
        for (int jj = 0; jj < 2; ++jj) { bF[1][jj][0] = rdB(buf, 2 + jj, 0); bF[1][jj][1] = rdB(buf, 2 + jj, 1); }
        __builtin_amdgcn_s_barrier();
        asm volatile("s_waitcnt lgkmcnt(0)" ::: "memory");
        __builtin_amdgcn_s_setprio(1);
#pragma unroll
        for (int ii = 0; ii < 2; ++ii)
#pragma unroll
            for (int jj = 0; jj < 2; ++jj)
#pragma unroll
                for (int kk = 0; kk < 2; ++kk)
                    acc[ii][2 + jj] = __builtin_amdgcn_mfma_f32_16x16x32_bf16(aF[ii][kk], bF[1][jj][kk], acc[ii][2 + jj], 0, 0, 0);
        __builtin_amdgcn_s_setprio(0);
        __builtin_amdgcn_s_barrier();
#pragma unroll
        for (int ii = 0; ii < 2; ++ii) { aF[ii][0] = rdA(buf, 2 + ii, 0); aF[ii][1] = rdA(buf, 2 + ii, 1); }
        if (t < NT - 2) stage(Bb, ldb, n0, t + 2, bsb + buf * 32768);
        __builtin_amdgcn_s_barrier();
        asm volatile("s_waitcnt lgkmcnt(0)" ::: "memory");
        __builtin_amdgcn_s_setprio(1);
#pragma unroll
        for (int ii = 0; ii < 2; ++ii)
#pragma unroll
            for (int jj = 0; jj < 2; ++jj)
#pragma unroll
                for (int kk = 0; kk < 2; ++kk)
                    acc[2 + ii][2 + jj] = __builtin_amdgcn_mfma_f32_16x16x32_bf16(aF[ii][kk], bF[1][jj][kk], acc[2 + ii][2 + jj], 0, 0, 0);
        __builtin_amdgcn_s_setprio(0);
        __builtin_amdgcn_s_barrier();
        if (t < NT - 2) stage(Bb, ldb, n0 + 128, t + 2, bsb + buf * 32768 + 16384);
        __builtin_amdgcn_s_setprio(1);
#pragma unroll
        for (int ii = 0; ii < 2; ++ii)
#pragma unroll
            for (int jj = 0; jj < 2; ++jj)
#pragma unroll
                for (int kk = 0; kk < 2; ++kk)
                    acc[2 + ii][jj] = __builtin_amdgcn_mfma_f32_16x16x32_bf16(aF[ii][kk], bF[0][jj][kk], acc[2 + ii][jj], 0, 0, 0);
        __builtin_amdgcn_s_setprio(0);
        if (t < NT - 2) { asm volatile("s_waitcnt vmcnt(4)" ::: "memory"); }
        else            { asm volatile("s_waitcnt vmcnt(0)" ::: "memory"); }
        __builtin_amdgcn_s_barrier();
    }

    const size_t ybase = (size_t)bz * sY;
    const size_t rbase = (size_t)bz * sR;
#pragma unroll
    for (int i = 0; i < 4; ++i) {
#pragma unroll
        for (int r = 0; r < 4; ++r) {
            int m = m0 + wr * 64 + i * 16 + kq * 4 + r;
            float bm = (BIAS_MODE == 1) ? bias[m] : 0.f;
#pragma unroll
            for (int j = 0; j < 4; ++j) {
                int n = n0 + wc * 64 + j * 16 + lr;
                float vv = acc[i][j][r] * alpha + bm;
                if (BIAS_MODE == 2) vv += bias[n];
                if (RESID) vv += resid[rbase + (size_t)m * ldy + n];
                if (OUT_BF16)
                    ((__hip_bfloat16*)Yv)[ybase + (size_t)m * ldy + n] = __float2bfloat16(vv);
                else
                    ((float*)Yv)[ybase + (size_t)m * ldy + n] = vv;
            }
        }
    }
}

// ---------------------------------------------------------------------------
// Scores^T + fused 32-key-chunk softmax + transposed P write. (verified r2)
// ---------------------------------------------------------------------------
__global__ __launch_bounds__(512)
void scores_softmax8(const unsigned short* __restrict__ A,   // xnT (keys)
                     const unsigned short* __restrict__ Bm,  // u (queries)
                     unsigned short* __restrict__ P)
{
    __shared__ __align__(16) unsigned short lds[65536];   // 128 KiB
    char* asb = (char*)lds;            // A: [2 buf][2 half][128 rows][128 B]
    char* bsb = (char*)lds + 65536;    // B: same

    const int bid = blockIdx.x;
    const int bz = bid >> 4, t16 = bid & 15;
    const int by = t16 >> 2, bx = t16 & 3;
    const int m0 = by << 8, n0 = bx << 8;      // m = key, n = sq

    const size_t sAB = (size_t)S_ * 512;
    const unsigned short* Ab = A  + (size_t)bz * sAB;
    const unsigned short* Bb = Bm + (size_t)bz * sAB;

    const int tid = threadIdx.x, wave = tid >> 6, lane = tid & 63;
    const int wr = wave >> 2, wc = wave & 3;   // 2 x 4 wave grid
    const int lr = lane & 15, kq = lane >> 4;
    const int swz = (lr & 7) << 4;

    floatx4 acc[8][4] = {};
    short8 aF[4][2], bF[2][2][2];

    auto stage = [&](const unsigned short* __restrict__ G, int row0, int t,
                     char* base, int buf, int half) {
#pragma unroll
        for (int c = 0; c < 2; ++c) {
            int x = c * 8192 + tid * 16;
            int row = x >> 7;
            int colb = (x & 127) ^ ((row & 7) << 4);
            const unsigned short* ga = G + (((size_t)(row0 + row)) << 9) + (t << 6) + (colb >> 1);
            char* ldst = base + buf * 32768 + half * 16384 + c * 8192 + wave * 1024;
            __builtin_amdgcn_global_load_lds(
                (const __attribute__((address_space(1))) void*)ga,
                (__attribute__((address_space(3))) void*)ldst, 16, 0, 0);
        }
    };
    auto rdA = [&](int buf, int mh, int ii, int kk) {
        int byte = buf * 32768 + wr * 16384 + (mh * 64 + ii * 16 + lr) * 128
                 + ((kk * 64 + kq * 16) ^ swz);
        return *(const short8*)(asb + byte);
    };
    auto rdB = [&](int buf, int nh, int jj, int kk) {
        int trow = wc * 64 + (nh * 2 + jj) * 16 + lr;
        int byte = buf * 32768 + (trow >> 7) * 16384 + (trow & 127) * 128
                 + ((kk * 64 + kq * 16) ^ swz);
        return *(const short8*)(bsb + byte);
    };

    stage(Ab, m0,       0, asb, 0, 0);
    stage(Bb, n0,       0, bsb, 0, 0);
    stage(Bb, n0 + 128, 0, bsb, 0, 1);
    stage(Ab, m0 + 128, 0, asb, 0, 1);
    stage(Ab, m0,       1, asb, 1, 0);
    stage(Bb, n0,       1, bsb, 1, 0);
    stage(Bb, n0 + 128, 1, bsb, 1, 1);
    asm volatile("s_waitcnt vmcnt(6)" ::: "memory");
    __builtin_amdgcn_s_barrier();

    for (int t = 0; t < 8; ++t) {
        const int buf = t & 1;
        // phase 0: quad (0,0); stage A1(t+1) -> buf^1
#pragma unroll
        for (int ii = 0; ii < 4; ++ii) { aF[ii][0] = rdA(buf, 0, ii, 0); aF[ii][1] = rdA(buf, 0, ii, 1); }
#pragma unroll
        for (int jj = 0; jj < 2; ++jj) { bF[0][jj][0] = rdB(buf, 0, jj, 0); bF[0][jj][1] = rdB(buf, 0, jj, 1); }
        if (t < 7) stage(Ab, m0 + 128, t + 1, asb, (t + 1) & 1, 1);
        __builtin_amdgcn_s_barrier();
        asm volatile("s_waitcnt lgkmcnt(0)" ::: "memory");
        __builtin_amdgcn_s_setprio(1);
#pragma unroll
        for (int ii = 0; ii < 4; ++ii)
#pragma unroll
            for (int jj = 0; jj < 2; ++jj)
#pragma unroll
                for (int kk = 0; kk < 2; ++kk)
                    acc[ii][jj] = __builtin_amdgcn_mfma_f32_16x16x32_bf16(aF[ii][kk], bF[0][jj][kk], acc[ii][jj], 0, 0, 0);
        __builtin_amdgcn_s_setprio(0);
        __builtin_amdgcn_s_barrier();
        // phase 1: quad (0,1); no stage
#pragma unroll
        for (int jj = 0; jj < 2; ++jj) { bF[1][jj][0] = rdB(buf, 1, jj, 0); bF[1][jj][1] = rdB(buf, 1, jj, 1); }
        __builtin_amdgcn_s_barrier();
        asm volatile("s_waitcnt lgkmcnt(0)" ::: "memory");
        __builtin_amdgcn_s_setprio(1);
#pragma unroll
        for (int ii = 0; ii < 4; ++ii)
#pragma unroll
            for (int jj = 0; jj < 2; ++jj)
#pragma unroll
                for (int kk = 0; kk < 2; ++kk)
                    acc[ii][2 + jj] = __builtin_amdgcn_mfma_f32_16x16x32_bf16(aF[ii][kk], bF[1][jj][kk], acc[ii][2 + jj], 0, 0, 0);
        __builtin_amdgcn_s_setprio(0);
        __builtin_amdgcn_s_barrier();
        // phase 2: quad (1,1); stage B0(t+2)
#pragma unroll
        for (int ii = 0; ii < 4; ++ii) { aF[ii][0] = rdA(buf, 1, ii, 0); aF[ii][1] = rdA(buf, 1, ii, 1); }
        if (t < 6) stage(Bb, n0, t + 2, bsb, buf, 0);
        __builtin_amdgcn_s_barrier();
        asm volatile("s_waitcnt lgkmcnt(0)" ::: "memory");
        __builtin_amdgcn_s_setprio(1);
#pragma unroll
        for (int ii = 0; ii < 4; ++ii)
#pragma unroll
            for (int jj = 0; jj < 2; ++jj)
#pragma unroll
                for (int kk = 0; kk < 2; ++kk)
                    acc[4 + ii][2 + jj] = __builtin_amdgcn_mfma_f32_16x16x32_bf16(aF[ii][kk], bF[1][jj][kk], acc[4 + ii][2 + jj], 0, 0, 0);
        __builtin_amdgcn_s_setprio(0);
        __builtin_amdgcn_s_barrier();
        // phase 3: quad (1,0); stage A0(t+2)+B1(t+2); counted vmcnt
        if (t < 6) {
            stage(Ab, m0,       t + 2, asb, buf, 0);
            stage(Bb, n0 + 128, t + 2, bsb, buf, 1);
        }
        __builtin_amdgcn_s_setprio(1);
#pragma unroll
        for (int ii = 0; ii < 4; ++ii)
#pragma unroll
            for (int jj = 0; jj < 2; ++jj)
#pragma unroll
                for (int kk = 0; kk < 2; ++kk)
                    acc[4 + ii][jj] = __builtin_amdgcn_mfma_f32_16x16x32_bf16(aF[ii][kk], bF[0][jj][kk], acc[4 + ii][jj], 0, 0, 0);
        __builtin_amdgcn_s_setprio(0);
        if (t < 6) { asm volatile("s_waitcnt vmcnt(6)" ::: "memory"); }
        else       { asm volatile("s_waitcnt vmcnt(0)" ::: "memory"); }
        __builtin_amdgcn_s_barrier();
    }

    // softmax over 32-key chunks; write P^T tile into reused LDS (swizzled)
#pragma unroll
    for (int j = 0; j < 4; ++j) {
        int sqc = wc * 64 + j * 16 + lr;
        int srow = sqc * 512;
        int sxor = (sqc & 7) << 4;
#pragma unroll
        for (int h = 0; h < 4; ++h) {
            float v0[4], v1[4];
            float mx = -1e30f;
#pragma unroll
            for (int r = 0; r < 4; ++r) {
                v0[r] = acc[2 * h][j][r]     * 0.125f;
                v1[r] = acc[2 * h + 1][j][r] * 0.125f;
                mx = fmaxf(mx, fmaxf(v0[r], v1[r]));
            }
            mx = fmaxf(mx, __shfl_xor(mx, 16));
            mx = fmaxf(mx, __shfl_xor(mx, 32));
            float sm = 0.f;
#pragma unroll
            for (int r = 0; r < 4; ++r) {
                v0[r] = __expf(v0[r] - mx);
                v1[r] = __expf(v1[r] - mx);
                sm += v0[r] + v1[r];
            }
            sm += __shfl_xor(sm, 16);
            sm += __shfl_xor(sm, 32);
            float inv = 1.f / sm;
            short4v p0, p1;
#pragma unroll
            for (int r = 0; r < 4; ++r) {
                p0[r] = (short)f2bf(v0[r] * inv);
                p1[r] = (short)f2bf(v1[r] * inv);
            }
            int kb = (wr * 128 + h * 32 + kq * 4) * 2;
            *(short4v*)(asb + ((srow + kb) ^ sxor))      = p0;
            *(short4v*)(asb + ((srow + kb + 32) ^ sxor)) = p1;
        }
    }
    __syncthreads();

    const size_t pbase = ((size_t)bz << 20) + (size_t)n0 * 1024 + m0;
#pragma unroll
    for (int it = 0; it < 16; ++it) {
        int row = wave * 32 + it * 2 + (lane >> 5);
        int colb = (lane & 31) << 4;
        short8 v = *(const short8*)(asb + ((row * 512 + colb) ^ ((row & 7) << 4)));
        *(short8*)(P + pbase + (size_t)row * 1024 + (colb >> 1)) = v;
    }
}

// ---------------------------------------------------------------------------
extern "C" void kernel_launch(void* const* d_in, const int* in_sizes, int n_in,
                              void* d_out, int out_size, void* d_ws, size_t ws_size,
                              hipStream_t stream) {
    const float* x     = (const float*)d_in[0];
    const float* gn_w  = (const float*)d_in[1];
    const float* gn_b  = (const float*)d_in[2];
    const float* qkv_w = (const float*)d_in[3];
    const float* qkv_b = (const float*)d_in[4];
    const float* pr_w  = (const float*)d_in[5];
    const float* pr_b  = (const float*)d_in[6];
    float* out = (float*)d_out;

    char* w = (char*)d_ws;
    __hip_bfloat16* xnT  = (__hip_bfloat16*)w;                     // 16 MiB [16][1024][512]
    __hip_bfloat16* u    = (__hip_bfloat16*)(w + (16u << 20));     // 16 MiB [16][1024][512]
    __hip_bfloat16* Vp   = (__hip_bfloat16*)(w + (32u << 20));     // 16 MiB [16][512][1024]
    __hip_bfloat16* P    = (__hip_bfloat16*)(w + (48u << 20));     // 32 MiB [16][1024][1024]
    unsigned short* bufX = (unsigned short*)(w + (80u << 20));     // 1 MiB [WkT | wp_bf]
    unsigned short* bufY = (unsigned short*)(w + (81u << 20));     // 1 MiB [WqT | WvT]
    unsigned short* bufZ = (unsigned short*)(w + (82u << 20));     // 1 MiB [MT | W']
    float*          bqWk = (float*)(w + (83u << 20));              // 2 KiB
    float*          bvp  = (float*)(w + (83u << 20) + 4096);       // 2 KiB

    // 0) zero the bqWk accumulator (atomics target)
    hipMemsetAsync(bqWk, 0, 512 * sizeof(float), stream);

    // 1) prep: transposes -> bf16, wp convert, parallel bias matvecs
    prep_kernel<<<392, 256, 0, stream>>>(qkv_w, pr_w, qkv_b, bufX, bufY, bqWk, bvp);

    // 2) [merge] GroupNorm -> xnT  ||  MT/W' weight GEMMs (s3 hidden under gn)
    gn_plus_w<<<544, 256, 0, stream>>>(x, gn_w, gn_b, xnT, bufX, bufY, bufZ);

    // 3) [merge] u = xnT.MT^T + bqWk  ||  V' = W'.xnT^T + bvp  (8-phase)
    fused_s45<<<512, 512, 0, stream>>>((const unsigned short*)xnT, bufZ, bqWk, bvp,
                                       u, Vp);

    // 4) scores^T + fused softmax + transpose -> P[sq][key]  (8-phase 256^2)
    scores_softmax8<<<256, 512, 0, stream>>>(
        (const unsigned short*)xnT, (const unsigned short*)u, (unsigned short*)P);

    // 5) out = V' . P^T + pr_b[m] + x   batched: M=512(c), N=1024(sq), K=1024
    gemm8ph<1, false, true, true, 1024><<<256, 512, 0, stream>>>(
        (const unsigned short*)Vp, (const unsigned short*)P, pr_b, x, out,
        1024, 1024, 1024, (size_t)512 * S_, (size_t)S_ * S_, (size_t)512 * S_,
        (size_t)512 * S_, 1.f, 4, 2);
}

// Round 6
// 189.223 us; speedup vs baseline: 1.1470x; 1.0380x over previous
//
#include <hip/hip_runtime.h>
#include <hip/hip_bf16.h>

#define B_    16
#define C_    512
#define S_    1024      // H*W
#define NGRP  32
#define CPG   16

typedef __attribute__((ext_vector_type(8))) short  short8;
typedef __attribute__((ext_vector_type(4))) short  short4v;
typedef __attribute__((ext_vector_type(4))) float  floatx4;

__device__ __forceinline__ unsigned short f2bf(float f) {
    __hip_bfloat16 h = __float2bfloat16(f);
    unsigned short u;
    __builtin_memcpy(&u, &h, 2);
    return u;
}

// ---------------------------------------------------------------------------
// Prep: weight transposes->bf16, wp convert, parallel bias matvecs.
// ---------------------------------------------------------------------------
__global__ __launch_bounds__(256)
void prep_kernel(const float* __restrict__ qkv_w, const float* __restrict__ proj_w,
                 const float* __restrict__ qkv_b,
                 unsigned short* __restrict__ bufX,   // [WkT | wp_bf]
                 unsigned short* __restrict__ bufY,   // [WqT | WvT]
                 float* __restrict__ bqWk, float* __restrict__ biasvp)
{
    int blk = blockIdx.x;
    int tid = threadIdx.x;
    if (blk < 192) {
        __shared__ float T[64][65];
        int mat = blk >> 6, tile = blk & 63;
        int r0 = (tile >> 3) * 64, c0 = (tile & 7) * 64;  // dst[r0+i][c0+j] = src[c0+j][r0+i]
        const float* src; unsigned short* dst;
        if (mat == 0)      { src = qkv_w + 512 * 512;  dst = bufX; }
        else if (mat == 1) { src = qkv_w;              dst = bufY; }
        else               { src = qkv_w + 1024 * 512; dst = bufY + 262144; }
#pragma unroll
        for (int rr = 0; rr < 4; ++rr) {
            int sr = rr * 16 + (tid >> 4);
            int sc = (tid & 15) * 4;
            float4 v = *(const float4*)(src + (size_t)(c0 + sr) * 512 + r0 + sc);
            T[sc][sr] = v.x; T[sc + 1][sr] = v.y; T[sc + 2][sr] = v.z; T[sc + 3][sr] = v.w;
        }
        __syncthreads();
#pragma unroll
        for (int rr = 0; rr < 4; ++rr) {
            int dr = rr * 16 + (tid >> 4);
            int dc = (tid & 15) * 4;
            short4v o;
            o[0] = (short)f2bf(T[dr][dc]);     o[1] = (short)f2bf(T[dr][dc + 1]);
            o[2] = (short)f2bf(T[dr][dc + 2]); o[3] = (short)f2bf(T[dr][dc + 3]);
            *(short4v*)(dst + (size_t)(r0 + dr) * 512 + c0 + dc) = o;
        }
    } else if (blk < 256) {
        unsigned short* wp = bufX + 262144;
#pragma unroll
        for (int t = 0; t < 4; ++t) {
            int i = (blk - 192) * 4096 + t * 1024 + tid * 4;
            float4 v = *(const float4*)(proj_w + i);
            short4v o;
            o[0] = (short)f2bf(v.x); o[1] = (short)f2bf(v.y);
            o[2] = (short)f2bf(v.z); o[3] = (short)f2bf(v.w);
            *(short4v*)(wp + i) = o;
        }
    } else if (blk < 264) {
        int sub = blk - 256;
        int j = (sub & 1) * 256 + tid;
        int o0 = (sub >> 1) * 128;
        float acc = 0.f;
#pragma unroll 8
        for (int oo = 0; oo < 128; ++oo) {
            int o = o0 + oo;
            acc += qkv_b[o] * qkv_w[(size_t)(512 + o) * 512 + j];
        }
        atomicAdd(&bqWk[j], acc);
    } else {
        int wv = tid >> 6, lane = tid & 63;
        int c = (blk - 264) * 4 + wv;
        float s = 0.f;
#pragma unroll
        for (int t = 0; t < 8; ++t)
            s += proj_w[(size_t)c * 512 + t * 64 + lane] * qkv_b[1024 + t * 64 + lane];
        for (int off = 32; off > 0; off >>= 1) s += __shfl_down(s, off);
        if (lane == 0) biasvp[c] = s;
    }
}

// ---------------------------------------------------------------------------
// Merge 1: blocks 0..511 = fused GroupNorm -> xnT; blocks 512..543 = the two
// 512x512x512 weight GEMMs (2-phase 128^2), hidden under gn's memory time.
// ---------------------------------------------------------------------------
__global__ __launch_bounds__(256)
void gn_plus_w(const float* __restrict__ x, const float* __restrict__ gnw,
               const float* __restrict__ gnb, __hip_bfloat16* __restrict__ xnT,
               const unsigned short* __restrict__ bufX,
               const unsigned short* __restrict__ bufY,
               unsigned short* __restrict__ bufZ)
{
    __shared__ __align__(16) char smem[32832];   // 32 KiB gemm | 64 B gn-red
    int blk = blockIdx.x;
    int tid = threadIdx.x;

    if (blk < 512) {
        int b = blk >> 5, g = blk & 31;
        const float4* xp = (const float4*)(x + (size_t)blk * (CPG * S_));
        float4 vv[16];
        float s = 0.f, ss = 0.f;
#pragma unroll
        for (int r = 0; r < 16; ++r) {
            float4 v = xp[r * 256 + tid];
            vv[r] = v;
            s  += v.x + v.y + v.z + v.w;
            ss += v.x*v.x + v.y*v.y + v.z*v.z + v.w*v.w;
        }
        for (int off = 32; off > 0; off >>= 1) {
            s  += __shfl_down(s, off);
            ss += __shfl_down(ss, off);
        }
        float* red = (float*)(smem + 32768);   // [8] : sums | sumsq
        float* msh = (float*)(smem + 32800);   // [2] : mean, inv
        int wid = tid >> 6, lane = tid & 63;
        if (lane == 0) { red[wid] = s; red[4 + wid] = ss; }
        __syncthreads();
        if (tid == 0) {
            float a = 0.f, c = 0.f;
            for (int i = 0; i < 4; ++i) { a += red[i]; c += red[4 + i]; }
            float mean = a / (float)(CPG * S_);
            float var  = c / (float)(CPG * S_) - mean * mean;
            msh[0] = mean;
            msh[1] = rsqrtf(var + 1e-5f);
        }
        __syncthreads();
        float mean = msh[0], inv = msh[1];

        float sc[16], sh[16];
#pragma unroll
        for (int c = 0; c < 16; ++c) {
            float wc = gnw[g * 16 + c];
            sc[c] = inv * wc;
            sh[c] = gnb[g * 16 + c] - mean * inv * wc;
        }
#pragma unroll
        for (int kk = 0; kk < 4; ++kk) {
            unsigned short outp[16];
#pragma unroll
            for (int c = 0; c < 16; ++c) {
                float v = (kk == 0) ? vv[c].x : (kk == 1) ? vv[c].y : (kk == 2) ? vv[c].z : vv[c].w;
                outp[c] = f2bf(v * sc[c] + sh[c]);
            }
            int srow = 4 * tid + kk;
            unsigned short* dst = (unsigned short*)xnT + ((size_t)(b * S_ + srow) * C_ + g * 16);
            *(short8*)dst       = *(short8*)outp;
            *(short8*)(dst + 8) = *(short8*)(outp + 8);
        }
    } else {
        unsigned short* As = (unsigned short*)smem;          // 2*128*32
        unsigned short* Bs = (unsigned short*)(smem + 16384);
        int id = blk - 512;                 // 0..31
        int bx = id & 3, by = (id >> 2) & 3, bz = id >> 4;
        const unsigned short* Ab = bufX + (size_t)bz * 262144;
        const unsigned short* Bb = bufY + (size_t)bz * 262144;
        __hip_bfloat16* Y = (__hip_bfloat16*)bufZ + (size_t)bz * 262144;
        const int wave = tid >> 6, lane = tid & 63;
        const int m0 = by * 128, n0 = bx * 128;
        const int wr = wave >> 1, wc = wave & 1, lr = lane & 15, kq = lane >> 4;
        const int row0 = tid >> 2, kc0 = (tid & 3) << 3;

        floatx4 acc[4][4] = {};
        for (int k0 = 0; k0 < 512; k0 += 64) {
            __syncthreads();
#pragma unroll
            for (int kk = 0; kk < 2; ++kk) {
#pragma unroll
                for (int r = 0; r < 2; ++r) {
                    const unsigned short* ga = Ab + (size_t)(m0 + r * 64 + row0) * 512 + k0 + kk * 32 + kc0;
                    __builtin_amdgcn_global_load_lds(
                        (const __attribute__((address_space(1))) void*)ga,
                        (__attribute__((address_space(3))) void*)(As + kk * 4096 + (r * 256 + wave * 64) * 8),
                        16, 0, 0);
                    const unsigned short* gb = Bb + (size_t)(n0 + r * 64 + row0) * 512 + k0 + kk * 32 + kc0;
                    __builtin_amdgcn_global_load_lds(
                        (const __attribute__((address_space(1))) void*)gb,
                        (__attribute__((address_space(3))) void*)(Bs + kk * 4096 + (r * 256 + wave * 64) * 8),
                        16, 0, 0);
                }
            }
            __syncthreads();
#pragma unroll
            for (int kk = 0; kk < 2; ++kk) {
                short8 af[4], bfr[4];
#pragma unroll
                for (int i = 0; i < 4; ++i)
                    af[i] = *(const short8*)&As[kk * 4096 + (wr * 64 + i * 16 + lr) * 32 + kq * 8];
#pragma unroll
                for (int j = 0; j < 4; ++j)
                    bfr[j] = *(const short8*)&Bs[kk * 4096 + (wc * 64 + j * 16 + lr) * 32 + kq * 8];
#pragma unroll
                for (int i = 0; i < 4; ++i)
#pragma unroll
                    for (int j = 0; j < 4; ++j)
                        acc[i][j] = __builtin_amdgcn_mfma_f32_16x16x32_bf16(af[i], bfr[j], acc[i][j], 0, 0, 0);
            }
        }
#pragma unroll
        for (int i = 0; i < 4; ++i)
#pragma unroll
            for (int r = 0; r < 4; ++r) {
                int m = m0 + wr * 64 + i * 16 + kq * 4 + r;
#pragma unroll
                for (int j = 0; j < 4; ++j) {
                    int n = n0 + wc * 64 + j * 16 + lr;
                    Y[(size_t)m * 512 + n] = __float2bfloat16(acc[i][j][r]);
                }
            }
    }
}

// ---------------------------------------------------------------------------
// 256x256 8-phase NT GEMM body (K=512, lda=ldb=512). Staging + K-loop are the
// r2-verified scores_softmax8 structure VERBATIM (same slot lifetimes, same
// vmcnt counting, same t<7/t<6 guards); only the epilogue differs.
// acc[idx][j]: m = m0 + wr*128 + idx*16 + kq*4 + r, n = n0 + wc*64 + j*16 + lr.
// ---------------------------------------------------------------------------
template<int BIAS_MODE>
__device__ __forceinline__
void gemm256_body(char* lds, const unsigned short* __restrict__ Ab,
                  const unsigned short* __restrict__ Bb,
                  const float* __restrict__ bias,
                  __hip_bfloat16* __restrict__ Y,
                  int ldy, size_t ybase, int m0, int n0)
{
    char* asb = lds;            // A: [2 buf][2 half][128 rows][128 B]
    char* bsb = lds + 65536;    // B: same

    const int tid = threadIdx.x, wave = tid >> 6, lane = tid & 63;
    const int wr = wave >> 2, wc = wave & 3;   // 2 x 4 wave grid
    const int lr = lane & 15, kq = lane >> 4;
    const int swz = (lr & 7) << 4;

    floatx4 acc[8][4] = {};
    short8 aF[4][2], bF[2][2][2];

    auto stage = [&](const unsigned short* __restrict__ G, int row0, int t,
                     char* base, int buf, int half) {
#pragma unroll
        for (int c = 0; c < 2; ++c) {
            int x = c * 8192 + tid * 16;
            int row = x >> 7;
            int colb = (x & 127) ^ ((row & 7) << 4);
            const unsigned short* ga = G + (((size_t)(row0 + row)) << 9) + (t << 6) + (colb >> 1);
            char* ldst = base + buf * 32768 + half * 16384 + c * 8192 + wave * 1024;
            __builtin_amdgcn_global_load_lds(
                (const __attribute__((address_space(1))) void*)ga,
                (__attribute__((address_space(3))) void*)ldst, 16, 0, 0);
        }
    };
    auto rdA = [&](int buf, int mh, int ii, int kk) {
        int byte = buf * 32768 + wr * 16384 + (mh * 64 + ii * 16 + lr) * 128
                 + ((kk * 64 + kq * 16) ^ swz);
        return *(const short8*)(asb + byte);
    };
    auto rdB = [&](int buf, int nh, int jj, int kk) {
        int trow = wc * 64 + (nh * 2 + jj) * 16 + lr;
        int byte = buf * 32768 + (trow >> 7) * 16384 + (trow & 127) * 128
                 + ((kk * 64 + kq * 16) ^ swz);
        return *(const short8*)(bsb + byte);
    };

    stage(Ab, m0,       0, asb, 0, 0);
    stage(Bb, n0,       0, bsb, 0, 0);
    stage(Bb, n0 + 128, 0, bsb, 0, 1);
    stage(Ab, m0 + 128, 0, asb, 0, 1);
    stage(Ab, m0,       1, asb, 1, 0);
    stage(Bb, n0,       1, bsb, 1, 0);
    stage(Bb, n0 + 128, 1, bsb, 1, 1);
    asm volatile("s_waitcnt vmcnt(6)" ::: "memory");
    __builtin_amdgcn_s_barrier();

    for (int t = 0; t < 8; ++t) {
        const int buf = t & 1;
        // phase 0: quad (0,0); stage A1(t+1) -> buf^1
#pragma unroll
        for (int ii = 0; ii < 4; ++ii) { aF[ii][0] = rdA(buf, 0, ii, 0); aF[ii][1] = rdA(buf, 0, ii, 1); }
#pragma unroll
        for (int jj = 0; jj < 2; ++jj) { bF[0][jj][0] = rdB(buf, 0, jj, 0); bF[0][jj][1] = rdB(buf, 0, jj, 1); }
        if (t < 7) stage(Ab, m0 + 128, t + 1, asb, (t + 1) & 1, 1);
        __builtin_amdgcn_s_barrier();
        asm volatile("s_waitcnt lgkmcnt(0)" ::: "memory");
        __builtin_amdgcn_s_setprio(1);
#pragma unroll
        for (int ii = 0; ii < 4; ++ii)
#pragma unroll
            for (int jj = 0; jj < 2; ++jj)
#pragma unroll
                for (int kk = 0; kk < 2; ++kk)
                    acc[ii][jj] = __builtin_amdgcn_mfma_f32_16x16x32_bf16(aF[ii][kk], bF[0][jj][kk], acc[ii][jj], 0, 0, 0);
        __builtin_amdgcn_s_setprio(0);
        __builtin_amdgcn_s_barrier();
        // phase 1: quad (0,1); no stage
#pragma unroll
        for (int jj = 0; jj < 2; ++jj) { bF[1][jj][0] = rdB(buf, 1, jj, 0); bF[1][jj][1] = rdB(buf, 1, jj, 1); }
        __builtin_amdgcn_s_barrier();
        asm volatile("s_waitcnt lgkmcnt(0)" ::: "memory");
        __builtin_amdgcn_s_setprio(1);
#pragma unroll
        for (int ii = 0; ii < 4; ++ii)
#pragma unroll
            for (int jj = 0; jj < 2; ++jj)
#pragma unroll
                for (int kk = 0; kk < 2; ++kk)
                    acc[ii][2 + jj] = __builtin_amdgcn_mfma_f32_16x16x32_bf16(aF[ii][kk], bF[1][jj][kk], acc[ii][2 + jj], 0, 0, 0);
        __builtin_amdgcn_s_setprio(0);
        __builtin_amdgcn_s_barrier();
        // phase 2: quad (1,1); stage B0(t+2)
#pragma unroll
        for (int ii = 0; ii < 4; ++ii) { aF[ii][0] = rdA(buf, 1, ii, 0); aF[ii][1] = rdA(buf, 1, ii, 1); }
        if (t < 6) stage(Bb, n0, t + 2, bsb, buf, 0);
        __builtin_amdgcn_s_barrier();
        asm volatile("s_waitcnt lgkmcnt(0)" ::: "memory");
        __builtin_amdgcn_s_setprio(1);
#pragma unroll
        for (int ii = 0; ii < 4; ++ii)
#pragma unroll
            for (int jj = 0; jj < 2; ++jj)
#pragma unroll
                for (int kk = 0; kk < 2; ++kk)
                    acc[4 + ii][2 + jj] = __builtin_amdgcn_mfma_f32_16x16x32_bf16(aF[ii][kk], bF[1][jj][kk], acc[4 + ii][2 + jj], 0, 0, 0);
        __builtin_amdgcn_s_setprio(0);
        __builtin_amdgcn_s_barrier();
        // phase 3: quad (1,0); stage A0(t+2)+B1(t+2); counted vmcnt
        if (t < 6) {
            stage(Ab, m0,       t + 2, asb, buf, 0);
            stage(Bb, n0 + 128, t + 2, bsb, buf, 1);
        }
        __builtin_amdgcn_s_setprio(1);
#pragma unroll
        for (int ii = 0; ii < 4; ++ii)
#pragma unroll
            for (int jj = 0; jj < 2; ++jj)
#pragma unroll
                for (int kk = 0; kk < 2; ++kk)
                    acc[4 + ii][jj] = __builtin_amdgcn_mfma_f32_16x16x32_bf16(aF[ii][kk], bF[0][jj][kk], acc[4 + ii][jj], 0, 0, 0);
        __builtin_amdgcn_s_setprio(0);
        if (t < 6) { asm volatile("s_waitcnt vmcnt(6)" ::: "memory"); }
        else       { asm volatile("s_waitcnt vmcnt(0)" ::: "memory"); }
        __builtin_amdgcn_s_barrier();
    }

#pragma unroll
    for (int idx = 0; idx < 8; ++idx)
#pragma unroll
        for (int r = 0; r < 4; ++r) {
            int m = m0 + wr * 128 + idx * 16 + kq * 4 + r;
            float bm = (BIAS_MODE == 1) ? bias[m] : 0.f;
#pragma unroll
            for (int j = 0; j < 4; ++j) {
                int n = n0 + wc * 64 + j * 16 + lr;
                float vv = acc[idx][j][r] + bm;
                if (BIAS_MODE == 2) vv += bias[n];
                Y[ybase + (size_t)m * ldy + n] = __float2bfloat16(vv);
            }
        }
}

// ---------------------------------------------------------------------------
// Merge 2 (256^2 tiles): blocks 0..127 = u GEMM (s4, 64x2 tiles),
// 128..255 = V' GEMM (s5, 2x4 tiles x 16 batches, XCD-swizzled).
// Exactly 256 blocks -> 1 block/CU, full machine.
// ---------------------------------------------------------------------------
__global__ __launch_bounds__(512)
void fused_s45(const unsigned short* __restrict__ xnT,
               const unsigned short* __restrict__ bufZ,
               const float* __restrict__ bqWk, const float* __restrict__ bvp,
               __hip_bfloat16* __restrict__ u, __hip_bfloat16* __restrict__ Vp)
{
    __shared__ __align__(16) char lds[131072];   // 128 KiB
    int blk = blockIdx.x;
    if (blk < 128) {
        // s4: u = xnT . MT^T + bqWk[n]; M=16384, N=512, K=512
        int by = blk >> 1, bx = blk & 1;
        gemm256_body<2>(lds, xnT, bufZ, bqWk, u, 512, 0, by * 256, bx * 256);
    } else {
        // s5: V' = W' . xnT^T + bvp[m]; batched M=512, N=1024, K=512
        int lin = blk - 128;
        int xcd = lin & 7, sup = lin >> 3;       // sup 0..15
        int bz = xcd + ((sup >> 3) << 3);        // 16 batches
        int tile = sup & 7;
        int bx = tile & 3, by = tile >> 2;       // by 0..1, bx 0..3
        gemm256_body<1>(lds, bufZ + 262144, xnT + (size_t)bz * ((size_t)S_ * 512),
                        bvp, Vp, 1024, (size_t)bz * 512 * S_, by * 256, bx * 256);
    }
}

// ---------------------------------------------------------------------------
// 8-phase 128x256 NT GEMM standalone (s7: fp32 out + residual, KTOT=1024).
// Schedule identical to r4-verified gemm8ph.
// ---------------------------------------------------------------------------
template<int BIAS_MODE, bool OUT_BF16, bool RESID, bool SWIZ, int KTOT>
__global__ __launch_bounds__(512)
void gemm8ph(const unsigned short* __restrict__ A, const unsigned short* __restrict__ Bm,
             const float* __restrict__ bias, const float* __restrict__ resid,
             void* __restrict__ Yv,
             int lda, int ldb, int ldy,
             size_t sA, size_t sB, size_t sY, size_t sR, float alpha,
             int ntsh, int nxsh)
{
    __shared__ __align__(16) char lds[98304];
    char* asb = lds;
    char* bsb = lds + 32768;

    int bx, by, bz;
    if (SWIZ) {
        int lin = blockIdx.x;
        int xcd = lin & 7, sup = lin >> 3;
        bz = xcd + ((sup >> ntsh) << 3);
        int tile = sup & ((1 << ntsh) - 1);
        bx = tile & ((1 << nxsh) - 1);
        by = tile >> nxsh;
    } else { bx = blockIdx.x; by = blockIdx.y; bz = blockIdx.z; }

    const unsigned short* Ab = A  + (size_t)bz * sA;
    const unsigned short* Bb = Bm + (size_t)bz * sB;
    const int tid = threadIdx.x, wave = tid >> 6, lane = tid & 63;
    const int m0 = by * 128, n0 = bx * 256;
    const int wr = wave >> 2, wc = wave & 3;
    const int lr = lane & 15, kq = lane >> 4;
    const int swz = (lr & 7) << 4;

    floatx4 acc[4][4] = {};
    short8 aF[2][2], bF[2][2][2];

    auto stage = [&](const unsigned short* __restrict__ G, int ld, int grow,
                     int t, char* dstbase) {
#pragma unroll
        for (int c = 0; c < 2; ++c) {
            int x = c * 8192 + tid * 16;
            int row = x >> 7;
            int colb = (x & 127) ^ ((row & 7) << 4);
            const unsigned short* ga = G + (size_t)(grow + row) * ld + t * 64 + (colb >> 1);
            char* ldst = dstbase + c * 8192 + wave * 1024;
            __builtin_amdgcn_global_load_lds(
                (const __attribute__((address_space(1))) void*)ga,
                (__attribute__((address_space(3))) void*)ldst, 16, 0, 0);
        }
    };
    auto rdA = [&](int buf, int i, int kk) {
        int byte = buf * 16384 + (wr * 64 + i * 16 + lr) * 128
                 + ((kk * 64 + kq * 16) ^ swz);
        return *(const short8*)(asb + byte);
    };
    auto rdB = [&](int buf, int jn, int kk) {
        int row = wc * 64 + jn * 16 + lr;
        int byte = buf * 32768 + (row >> 7) * 16384 + (row & 127) * 128
                 + ((kk * 64 + kq * 16) ^ swz);
        return *(const short8*)(bsb + byte);
    };

    stage(Ab, lda, m0,       0, asb);
    stage(Bb, ldb, n0,       0, bsb);
    stage(Bb, ldb, n0 + 128, 0, bsb + 16384);
    stage(Bb, ldb, n0,       1, bsb + 32768);
    stage(Bb, ldb, n0 + 128, 1, bsb + 32768 + 16384);
    asm volatile("s_waitcnt vmcnt(4)" ::: "memory");
    __builtin_amdgcn_s_barrier();

    constexpr int NT = KTOT / 64;
    for (int t = 0; t < NT; ++t) {
        const int buf = t & 1;
#pragma unroll
        for (int ii = 0; ii < 2; ++ii) { aF[ii][0] = rdA(buf, ii, 0); aF[ii][1] = rdA(buf, ii, 1); }
#pragma unroll
        for (int jj = 0; jj < 2; ++jj) { bF[0][jj][0] = rdB(buf, jj, 0); bF[0][jj][1] = rdB(buf, jj, 1); }
        if (t < NT - 1) stage(Ab, lda, m0, t + 1, asb + ((t + 1) & 1) * 16384);
        __builtin_amdgcn_s_barrier();
        asm volatile("s_waitcnt lgkmcnt(0)" ::: "memory");
        __builtin_amdgcn_s_setprio(1);
#pragma unroll
        for (int ii = 0; ii < 2; ++ii)
#pragma unroll
            for (int jj = 0; jj < 2; ++jj)
#pragma unroll
                for (int kk = 0; kk < 2; ++kk)
                    acc[ii][jj] = __builtin_amdgcn_mfma_f32_16x16x32_bf16(aF[ii][kk], bF[0][jj][kk], acc[ii][jj], 0, 0, 0);
        __builtin_amdgcn_s_setprio(0);
        __builtin_amdgcn_s_barrier();
#pragma unroll
        for (int jj = 0; jj < 2; ++jj) { bF[1][jj][0] = rdB(buf, 2 + jj, 0); bF[1][jj][1] = rdB(buf, 2 + jj, 1); }
        __builtin_amdgcn_s_barrier();
        asm volatile("s_waitcnt lgkmcnt(0)" ::: "memory");
        __builtin_amdgcn_s_setprio(1);
#pragma unroll
        for (int ii = 0; ii < 2; ++ii)
#pragma unroll
            for (int jj = 0; jj < 2; ++jj)
#pragma unroll
                for (int kk = 0; kk < 2; ++kk)
                    acc[ii][2 + jj] = __builtin_amdgcn_mfma_f32_16x16x32_bf16(aF[ii][kk], bF[1][jj][kk], acc[ii][2 + jj], 0, 0, 0);
        __builtin_amdgcn_s_setprio(0);
        __builtin_amdgcn_s_barrier();
#pragma unroll
        for (int ii = 0; ii < 2; ++ii) { aF[ii][0] = rdA(buf, 2 + ii, 0); aF[ii][1] = rdA(buf, 2 + ii, 1); }
        if (t < NT - 2) stage(Bb, ldb, n0, t + 2, bsb + buf * 32768);
        __builtin_amdgcn_s_barrier();
        asm volatile("s_waitcnt lgkmcnt(0)" ::: "memory");
        __builtin_amdgcn_s_setprio(1);
#pragma unroll
        for (int ii = 0; ii < 2; ++ii)
#pragma unroll
            for (int jj = 0; jj < 2; ++jj)
#pragma unroll
                for (int kk = 0; kk < 2; ++kk)
                    acc[2 + ii][2 + jj] = __builtin_amdgcn_mfma_f32_16x16x32_bf16(aF[ii][kk], bF[1][jj][kk], acc[2 + ii][2 + jj], 0, 0, 0);
        __builtin_amdgcn_s_setprio(0);
        __builtin_amdgcn_s_barrier();
        if (t < NT - 2) stage(Bb, ldb, n0 + 128, t + 2, bsb + buf * 32768 + 16384);
        __builtin_amdgcn_s_setprio(1);
#pragma unroll
        for (int ii = 0; ii < 2; ++ii)
#pragma unroll
            for (int jj = 0; jj < 2; ++jj)
#pragma unroll
                for (int kk = 0; kk < 2; ++kk)
                    acc[2 + ii][jj] = __builtin_amdgcn_mfma_f32_16x16x32_bf16(aF[ii][kk], bF[0][jj][kk], acc[2 + ii][jj], 0, 0, 0);
        __builtin_amdgcn_s_setprio(0);
        if (t < NT - 2) { asm volatile("s_waitcnt vmcnt(4)" ::: "memory"); }
        else            { asm volatile("s_waitcnt vmcnt(0)" ::: "memory"); }
        __builtin_amdgcn_s_barrier();
    }

    const size_t ybase = (size_t)bz * sY;
    const size_t rbase = (size_t)bz * sR;
#pragma unroll
    for (int i = 0; i < 4; ++i) {
#pragma unroll
        for (int r = 0; r < 4; ++r) {
            int m = m0 + wr * 64 + i * 16 + kq * 4 + r;
            float bm = (BIAS_MODE == 1) ? bias[m] : 0.f;
#pragma unroll
            for (int j = 0; j < 4; ++j) {
                int n = n0 + wc * 64 + j * 16 + lr;
                float vv = acc[i][j][r] * alpha + bm;
                if (BIAS_MODE == 2) vv += bias[n];
                if (RESID) vv += resid[rbase + (size_t)m * ldy + n];
                if (OUT_BF16)
                    ((__hip_bfloat16*)Yv)[ybase + (size_t)m * ldy + n] = __float2bfloat16(vv);
                else
                    ((float*)Yv)[ybase + (size_t)m * ldy + n] = vv;
            }
        }
    }
}

// ---------------------------------------------------------------------------
// Scores^T + fused 32-key-chunk softmax + transposed P write. (verified r2)
// ---------------------------------------------------------------------------
__global__ __launch_bounds__(512)
void scores_softmax8(const unsigned short* __restrict__ A,   // xnT (keys)
                     const unsigned short* __restrict__ Bm,  // u (queries)
                     unsigned short* __restrict__ P)
{
    __shared__ __align__(16) unsigned short lds[65536];   // 128 KiB
    char* asb = (char*)lds;            // A: [2 buf][2 half][128 rows][128 B]
    char* bsb = (char*)lds + 65536;    // B: same

    const int bid = blockIdx.x;
    const int bz = bid >> 4, t16 = bid & 15;
    const int by = t16 >> 2, bx = t16 & 3;
    const int m0 = by << 8, n0 = bx << 8;      // m = key, n = sq

    const size_t sAB = (size_t)S_ * 512;
    const unsigned short* Ab = A  + (size_t)bz * sAB;
    const unsigned short* Bb = Bm + (size_t)bz * sAB;

    const int tid = threadIdx.x, wave = tid >> 6, lane = tid & 63;
    const int wr = wave >> 2, wc = wave & 3;   // 2 x 4 wave grid
    const int lr = lane & 15, kq = lane >> 4;
    const int swz = (lr & 7) << 4;

    floatx4 acc[8][4] = {};
    short8 aF[4][2], bF[2][2][2];

    auto stage = [&](const unsigned short* __restrict__ G, int row0, int t,
                     char* base, int buf, int half) {
#pragma unroll
        for (int c = 0; c < 2; ++c) {
            int x = c * 8192 + tid * 16;
            int row = x >> 7;
            int colb = (x & 127) ^ ((row & 7) << 4);
            const unsigned short* ga = G + (((size_t)(row0 + row)) << 9) + (t << 6) + (colb >> 1);
            char* ldst = base + buf * 32768 + half * 16384 + c * 8192 + wave * 1024;
            __builtin_amdgcn_global_load_lds(
                (const __attribute__((address_space(1))) void*)ga,
                (__attribute__((address_space(3))) void*)ldst, 16, 0, 0);
        }
    };
    auto rdA = [&](int buf, int mh, int ii, int kk) {
        int byte = buf * 32768 + wr * 16384 + (mh * 64 + ii * 16 + lr) * 128
                 + ((kk * 64 + kq * 16) ^ swz);
        return *(const short8*)(asb + byte);
    };
    auto rdB = [&](int buf, int nh, int jj, int kk) {
        int trow = wc * 64 + (nh * 2 + jj) * 16 + lr;
        int byte = buf * 32768 + (trow >> 7) * 16384 + (trow & 127) * 128
                 + ((kk * 64 + kq * 16) ^ swz);
        return *(const short8*)(bsb + byte);
    };

    stage(Ab, m0,       0, asb, 0, 0);
    stage(Bb, n0,       0, bsb, 0, 0);
    stage(Bb, n0 + 128, 0, bsb, 0, 1);
    stage(Ab, m0 + 128, 0, asb, 0, 1);
    stage(Ab, m0,       1, asb, 1, 0);
    stage(Bb, n0,       1, bsb, 1, 0);
    stage(Bb, n0 + 128, 1, bsb, 1, 1);
    asm volatile("s_waitcnt vmcnt(6)" ::: "memory");
    __builtin_amdgcn_s_barrier();

    for (int t = 0; t < 8; ++t) {
        const int buf = t & 1;
        // phase 0: quad (0,0); stage A1(t+1) -> buf^1
#pragma unroll
        for (int ii = 0; ii < 4; ++ii) { aF[ii][0] = rdA(buf, 0, ii, 0); aF[ii][1] = rdA(buf, 0, ii, 1); }
#pragma unroll
        for (int jj = 0; jj < 2; ++jj) { bF[0][jj][0] = rdB(buf, 0, jj, 0); bF[0][jj][1] = rdB(buf, 0, jj, 1); }
        if (t < 7) stage(Ab, m0 + 128, t + 1, asb, (t + 1) & 1, 1);
        __builtin_amdgcn_s_barrier();
        asm volatile("s_waitcnt lgkmcnt(0)" ::: "memory");
        __builtin_amdgcn_s_setprio(1);
#pragma unroll
        for (int ii = 0; ii < 4; ++ii)
#pragma unroll
            for (int jj = 0; jj < 2; ++jj)
#pragma unroll
                for (int kk = 0; kk < 2; ++kk)
                    acc[ii][jj] = __builtin_amdgcn_mfma_f32_16x16x32_bf16(aF[ii][kk], bF[0][jj][kk], acc[ii][jj], 0, 0, 0);
        __builtin_amdgcn_s_setprio(0);
        __builtin_amdgcn_s_barrier();
        // phase 1: quad (0,1); no stage
#pragma unroll
        for (int jj = 0; jj < 2; ++jj) { bF[1][jj][0] = rdB(buf, 1, jj, 0); bF[1][jj][1] = rdB(buf, 1, jj, 1); }
        __builtin_amdgcn_s_barrier();
        asm volatile("s_waitcnt lgkmcnt(0)" ::: "memory");
        __builtin_amdgcn_s_setprio(1);
#pragma unroll
        for (int ii = 0; ii < 4; ++ii)
#pragma unroll
            for (int jj = 0; jj < 2; ++jj)
#pragma unroll
                for (int kk = 0; kk < 2; ++kk)
                    acc[ii][2 + jj] = __builtin_amdgcn_mfma_f32_16x16x32_bf16(aF[ii][kk], bF[1][jj][kk], acc[ii][2 + jj], 0, 0, 0);
        __builtin_amdgcn_s_setprio(0);
        __builtin_amdgcn_s_barrier();
        // phase 2: quad (1,1); stage B0(t+2)
#pragma unroll
        for (int ii = 0; ii < 4; ++ii) { aF[ii][0] = rdA(buf, 1, ii, 0); aF[ii][1] = rdA(buf, 1, ii, 1); }
        if (t < 6) stage(Bb, n0, t + 2, bsb, buf, 0);
        __builtin_amdgcn_s_barrier();
        asm volatile("s_waitcnt lgkmcnt(0)" ::: "memory");
        __builtin_amdgcn_s_setprio(1);
#pragma unroll
        for (int ii = 0; ii < 4; ++ii)
#pragma unroll
            for (int jj = 0; jj < 2; ++jj)
#pragma unroll
                for (int kk = 0; kk < 2; ++kk)
                    acc[4 + ii][2 + jj] = __builtin_amdgcn_mfma_f32_16x16x32_bf16(aF[ii][kk], bF[1][jj][kk], acc[4 + ii][2 + jj], 0, 0, 0);
        __builtin_amdgcn_s_setprio(0);
        __builtin_amdgcn_s_barrier();
        // phase 3: quad (1,0); stage A0(t+2)+B1(t+2); counted vmcnt
        if (t < 6) {
            stage(Ab, m0,       t + 2, asb, buf, 0);
            stage(Bb, n0 + 128, t + 2, bsb, buf, 1);
        }
        __builtin_amdgcn_s_setprio(1);
#pragma unroll
        for (int ii = 0; ii < 4; ++ii)
#pragma unroll
            for (int jj = 0; jj < 2; ++jj)
#pragma unroll
                for (int kk = 0; kk < 2; ++kk)
                    acc[4 + ii][jj] = __builtin_amdgcn_mfma_f32_16x16x32_bf16(aF[ii][kk], bF[0][jj][kk], acc[4 + ii][jj], 0, 0, 0);
        __builtin_amdgcn_s_setprio(0);
        if (t < 6) { asm volatile("s_waitcnt vmcnt(6)" ::: "memory"); }
        else       { asm volatile("s_waitcnt vmcnt(0)" ::: "memory"); }
        __builtin_amdgcn_s_barrier();
    }

    // softmax over 32-key chunks; write P^T tile into reused LDS (swizzled)
#pragma unroll
    for (int j = 0; j < 4; ++j) {
        int sqc = wc * 64 + j * 16 + lr;
        int srow = sqc * 512;
        int sxor = (sqc & 7) << 4;
#pragma unroll
        for (int h = 0; h < 4; ++h) {
            float v0[4], v1[4];
            float mx = -1e30f;
#pragma unroll
            for (int r = 0; r < 4; ++r) {
                v0[r] = acc[2 * h][j][r]     * 0.125f;
                v1[r] = acc[2 * h + 1][j][r] * 0.125f;
                mx = fmaxf(mx, fmaxf(v0[r], v1[r]));
            }
            mx = fmaxf(mx, __shfl_xor(mx, 16));
            mx = fmaxf(mx, __shfl_xor(mx, 32));
            float sm = 0.f;
#pragma unroll
            for (int r = 0; r < 4; ++r) {
                v0[r] = __expf(v0[r] - mx);
                v1[r] = __expf(v1[r] - mx);
                sm += v0[r] + v1[r];
            }
            sm += __shfl_xor(sm, 16);
            sm += __shfl_xor(sm, 32);
            float inv = 1.f / sm;
            short4v p0, p1;
#pragma unroll
            for (int r = 0; r < 4; ++r) {
                p0[r] = (short)f2bf(v0[r] * inv);
                p1[r] = (short)f2bf(v1[r] * inv);
            }
            int kb = (wr * 128 + h * 32 + kq * 4) * 2;
            *(short4v*)(asb + ((srow + kb) ^ sxor))      = p0;
            *(short4v*)(asb + ((srow + kb + 32) ^ sxor)) = p1;
        }
    }
    __syncthreads();

    const size_t pbase = ((size_t)bz << 20) + (size_t)n0 * 1024 + m0;
#pragma unroll
    for (int it = 0; it < 16; ++it) {
        int row = wave * 32 + it * 2 + (lane >> 5);
        int colb = (lane & 31) << 4;
        short8 v = *(const short8*)(asb + ((row * 512 + colb) ^ ((row & 7) << 4)));
        *(short8*)(P + pbase + (size_t)row * 1024 + (colb >> 1)) = v;
    }
}

// ---------------------------------------------------------------------------
extern "C" void kernel_launch(void* const* d_in, const int* in_sizes, int n_in,
                              void* d_out, int out_size, void* d_ws, size_t ws_size,
                              hipStream_t stream) {
    const float* x     = (const float*)d_in[0];
    const float* gn_w  = (const float*)d_in[1];
    const float* gn_b  = (const float*)d_in[2];
    const float* qkv_w = (const float*)d_in[3];
    const float* qkv_b = (const float*)d_in[4];
    const float* pr_w  = (const float*)d_in[5];
    const float* pr_b  = (const float*)d_in[6];
    float* out = (float*)d_out;

    char* w = (char*)d_ws;
    __hip_bfloat16* xnT  = (__hip_bfloat16*)w;                     // 16 MiB [16][1024][512]
    __hip_bfloat16* u    = (__hip_bfloat16*)(w + (16u << 20));     // 16 MiB [16][1024][512]
    __hip_bfloat16* Vp   = (__hip_bfloat16*)(w + (32u << 20));     // 16 MiB [16][512][1024]
    __hip_bfloat16* P    = (__hip_bfloat16*)(w + (48u << 20));     // 32 MiB [16][1024][1024]
    unsigned short* bufX = (unsigned short*)(w + (80u << 20));     // 1 MiB [WkT | wp_bf]
    unsigned short* bufY = (unsigned short*)(w + (81u << 20));     // 1 MiB [WqT | WvT]
    unsigned short* bufZ = (unsigned short*)(w + (82u << 20));     // 1 MiB [MT | W']
    float*          bqWk = (float*)(w + (83u << 20));              // 2 KiB
    float*          bvp  = (float*)(w + (83u << 20) + 4096);       // 2 KiB

    // 0) zero the bqWk accumulator (atomics target)
    hipMemsetAsync(bqWk, 0, 512 * sizeof(float), stream);

    // 1) prep: transposes -> bf16, wp convert, parallel bias matvecs
    prep_kernel<<<392, 256, 0, stream>>>(qkv_w, pr_w, qkv_b, bufX, bufY, bqWk, bvp);

    // 2) [merge] GroupNorm -> xnT  ||  MT/W' weight GEMMs (s3 hidden under gn)
    gn_plus_w<<<544, 256, 0, stream>>>(x, gn_w, gn_b, xnT, bufX, bufY, bufZ);

    // 3) [merge] u = xnT.MT^T + bqWk  ||  V' = W'.xnT^T + bvp  (256^2 8-phase)
    fused_s45<<<256, 512, 0, stream>>>((const unsigned short*)xnT, bufZ, bqWk, bvp,
                                       u, Vp);

    // 4) scores^T + fused softmax + transpose -> P[sq][key]  (8-phase 256^2)
    scores_softmax8<<<256, 512, 0, stream>>>(
        (const unsigned short*)xnT, (const unsigned short*)u, (unsigned short*)P);

    // 5) out = V' . P^T + pr_b[m] + x   batched: M=512(c), N=1024(sq), K=1024
    gemm8ph<1, false, true, true, 1024><<<256, 512, 0, stream>>>(
        (const unsigned short*)Vp, (const unsigned short*)P, pr_b, x, out,
        1024, 1024, 1024, (size_t)512 * S_, (size_t)S_ * S_, (size_t)512 * S_,
        (size_t)512 * S_, 1.f, 4, 2);
}